// Round 4
// baseline (2250.746 us; speedup 1.0000x reference)
//
#include <hip/hip_runtime.h>
#include <math.h>

#define DEVINL __device__ __forceinline__

constexpr int B_ = 64;
constexpr int N_ = 3136;
constexpr int C_ = 64;        // DIM
constexpr int NG = 49;        // N_grid
constexpr int NSAMP = 784;    // SAMPLE_NUM
constexpr int ND = NG + NSAMP;     // 833
constexpr int NREST = N_ - NG;     // 3087
constexpr int H_ = 56, W_ = 56;
constexpr int HW = H_ * W_;        // 3136
constexpr int NS = 14 * 14;        // 196 tokens after strided conv
constexpr float LN_EPS = 1e-5f;
constexpr float EPS6 = 1e-6f;

// ---------------------------------------------------------------------------
// K1: conf scores in FP64 (discrete top-k decision must match f64 np ref)
// ---------------------------------------------------------------------------
__global__ __launch_bounds__(256) void k_conf(
    const float* __restrict__ x, const float* __restrict__ ng, const float* __restrict__ nb,
    const float* __restrict__ cw, const float* __restrict__ cb,
    const float* __restrict__ nu, double* __restrict__ scores) {
  int t = blockIdx.x * 256 + threadIdx.x;
  if (t >= B_ * N_) return;
  int b = t / N_, n = t - b * N_;
  if (n < NG) return;
  const float4* row = (const float4*)(x + (size_t)t * C_);
  float v[C_];
#pragma unroll
  for (int i = 0; i < 16; ++i) {
    float4 r = row[i];
    v[4*i] = r.x; v[4*i+1] = r.y; v[4*i+2] = r.z; v[4*i+3] = r.w;
  }
  double sd = 0.0;
#pragma unroll
  for (int i = 0; i < C_; ++i) sd += (double)v[i];
  double md = sd * (1.0/64.0);
  double vd = 0.0;
#pragma unroll
  for (int i = 0; i < C_; ++i) { double d = (double)v[i] - md; vd += d * d; }
  vd *= (1.0/64.0);
  double rsd = 1.0 / sqrt(vd + 1e-5);
  double conf = (double)cb[0];
#pragma unroll
  for (int i = 0; i < C_; ++i) {
    double xnv = ((double)v[i] - md) * rsd;
    conf += (xnv * (double)ng[i] + (double)nb[i]) * (double)cw[i];
  }
  double u = (double)nu[(size_t)b * NREST + (n - NG)];
  double noise = -log(-log(u + 1e-6) + 1e-6);
  scores[(size_t)b * NREST + (n - NG)] = conf + noise;
}

// ---------------------------------------------------------------------------
// K2: per-batch top-784 of 3087 via bitonic sort of (f64-key, idx) in LDS.
// Descending score, ties -> lower idx (matches jax.lax.top_k).
// ---------------------------------------------------------------------------
__global__ __launch_bounds__(256) void k_topk(const double* __restrict__ scores, int* __restrict__ idx) {
  __shared__ unsigned long long ks[4096];
  __shared__ unsigned int is_[4096];
  int b = blockIdx.x;
  int tid = threadIdx.x;
  const double* sc = scores + (size_t)b * NREST;
  for (int i = tid; i < 4096; i += 256) {
    if (i < NREST) {
      long long bits = __double_as_longlong(sc[i]);
      unsigned long long ub = (unsigned long long)bits;
      ub = (bits < 0) ? ~ub : (ub | 0x8000000000000000ULL);  // monotone map
      ks[i] = ~ub;               // ascending key == descending score
      is_[i] = (unsigned int)i;
    } else {
      ks[i] = 0xFFFFFFFFFFFFFFFFULL;
      is_[i] = 0xFFFFFFFFu;
    }
  }
  __syncthreads();
  for (int k = 2; k <= 4096; k <<= 1) {
    for (int j = k >> 1; j > 0; j >>= 1) {
      for (int i = tid; i < 4096; i += 256) {
        int l = i ^ j;
        if (l > i) {
          unsigned long long ka = ks[i], kc = ks[l];
          unsigned int ia = is_[i], ic = is_[l];
          bool agtc = (ka > kc) || (ka == kc && ia > ic);
          bool up = ((i & k) == 0);
          if (up == agtc) { ks[i] = kc; ks[l] = ka; is_[i] = ic; is_[l] = ia; }
        }
      }
      __syncthreads();
    }
  }
  for (int r = tid; r < NSAMP; r += 256)
    idx[(size_t)b * NSAMP + r] = (int)is_[r];
}

// ---------------------------------------------------------------------------
// K3: gather x_down/pos_down rows; LayerNorm(x_down, norm1) -> xn
// ---------------------------------------------------------------------------
__global__ __launch_bounds__(256) void k_gather_ln(
    const float* __restrict__ x, const float* __restrict__ pos, const int* __restrict__ idx,
    const float* __restrict__ n1g, const float* __restrict__ n1b,
    float* __restrict__ xd, float* __restrict__ xn, float* __restrict__ pd) {
  int t = blockIdx.x * 256 + threadIdx.x;
  if (t >= B_ * ND) return;
  int b = t / ND, r = t - b * ND;
  int srcn = (r < NG) ? r : (NG + idx[(size_t)b * NSAMP + (r - NG)]);
  const float4* row = (const float4*)(x + ((size_t)b * N_ + srcn) * C_);
  float4* xdr = (float4*)(xd + (size_t)t * C_);
  float v[C_];
  float s = 0.f, ss = 0.f;
#pragma unroll
  for (int i = 0; i < 16; ++i) {
    float4 rr = row[i];
    xdr[i] = rr;
    v[4*i] = rr.x; v[4*i+1] = rr.y; v[4*i+2] = rr.z; v[4*i+3] = rr.w;
    s += rr.x + rr.y + rr.z + rr.w;
    ss += rr.x*rr.x + rr.y*rr.y + rr.z*rr.z + rr.w*rr.w;
  }
  float m = s * (1.f/64.f);
  float var = ss * (1.f/64.f) - m*m;
  float rs = rsqrtf(var + LN_EPS);
#pragma unroll
  for (int i = 0; i < C_; ++i)
    xn[(size_t)t * C_ + i] = (v[i] - m) * rs * n1g[i] + n1b[i];
  pd[(size_t)2*t]   = pos[((size_t)b * N_ + srcn) * 2];
  pd[(size_t)2*t+1] = pos[((size_t)b * N_ + srcn) * 2 + 1];
}

// ---------------------------------------------------------------------------
// K4: scatter: recompute LN(x,norm1) inline (f32), f64 bin assignment,
// atomicAdd into S[b][pixel][65]
// ---------------------------------------------------------------------------
__global__ __launch_bounds__(256) void k_scatter(
    const float* __restrict__ x, const float* __restrict__ n1g, const float* __restrict__ n1b,
    const float* __restrict__ pos, float* __restrict__ S) {
  int t = blockIdx.x * 256 + threadIdx.x;
  if (t >= B_ * N_) return;
  int b = t / N_;
  const float4* row = (const float4*)(x + (size_t)t * C_);
  float v[C_];
  float s = 0.f, ss = 0.f;
#pragma unroll
  for (int i = 0; i < 16; ++i) {
    float4 r = row[i];
    v[4*i] = r.x; v[4*i+1] = r.y; v[4*i+2] = r.z; v[4*i+3] = r.w;
    s += r.x + r.y + r.z + r.w;
    ss += r.x*r.x + r.y*r.y + r.z*r.z + r.w*r.w;
  }
  float m = s * (1.f/64.f);
  float var = ss * (1.f/64.f) - m*m;
  float rs = rsqrtf(var + LN_EPS);
  double px = fmin(fmax((double)pos[(size_t)2*t],   0.0), 1.0) * (double)(W_ - 1);
  double py = fmin(fmax((double)pos[(size_t)2*t+1], 0.0), 1.0) * (double)(H_ - 1);
  int xi = (int)rint(px), yi = (int)rint(py);
  float* base = S + ((size_t)b * HW + yi * W_ + xi) * 65;
#pragma unroll 8
  for (int c = 0; c < C_; ++c) atomicAdd(base + c, (v[c] - m) * rs * n1g[c] + n1b[c]);
  atomicAdd(base + 64, 1.f);
}

// ---------------------------------------------------------------------------
// K5: normalize + masked 3x3 gaussian reconstruct -> conv-patch layout (f32)
// P[b*196+j][ci*16+ky*4+kx]
// ---------------------------------------------------------------------------
__global__ __launch_bounds__(256) void k_filter(const float* __restrict__ S, float* __restrict__ P) {
  int t = blockIdx.x * 256 + threadIdx.x;
  if (t >= B_ * HW) return;
  int b = t / HW, p = t - b * HW;
  int y = p / W_, x = p - y * W_;
  const float* Sb = S + (size_t)b * HW * 65;
  const float e1 = 0.882496902584595f;   // exp(-1/8)
  const float e2 = 0.778800783071405f;   // exp(-1/4)
  const float Z = 1.f + 4.f * (e1 + e2);
  float m0 = Sb[(size_t)p * 65 + 64];
  float mb0 = m0 > 0.f ? 1.f : 0.f;
  float cfac = mb0 / (m0 + EPS6);
  float scale[9];
  int off[9];
  float mi = 0.f;
  int kk = 0;
#pragma unroll
  for (int dy = -1; dy <= 1; ++dy) {
#pragma unroll
    for (int dx = -1; dx <= 1; ++dx) {
      int ny = y + dy, nx = x + dx;
      float w = ((dx == 0 && dy == 0) ? 1.f : ((dx*dx + dy*dy) == 1 ? e1 : e2)) / Z;
      bool in = (ny >= 0 && ny < H_ && nx >= 0 && nx < W_);
      int np = in ? (ny * W_ + nx) : p;
      float mm = in ? Sb[(size_t)np * 65 + 64] : 0.f;
      float mb = mm > 0.f ? 1.f : 0.f;
      mi += w * mb;
      scale[kk] = in ? (w * mb / (mm + EPS6)) : 0.f;
      off[kk] = np * 65;
      ++kk;
    }
  }
  float inv_mi = (mi > 0.f ? 1.f : 0.f) / (mi + EPS6);
  float outer = (1.f - mb0) * inv_mi;
  int j = (y >> 2) * 14 + (x >> 2);
  int colb = (y & 3) * 4 + (x & 3);
  float* Pr = P + ((size_t)b * NS + j) * 1024 + colb;
  size_t pc = (size_t)p * 65;
  for (int c = 0; c < C_; ++c) {
    float fs = 0.f;
#pragma unroll
    for (int q = 0; q < 9; ++q) fs += scale[q] * Sb[(size_t)off[q] + c];
    Pr[c * 16] = Sb[pc + c] * cfac + outer * fs;
  }
}

// ---------------------------------------------------------------------------
// K6: transpose sr_w (co,ci,ky,kx) -> w_t[kk=ci*16+ky*4+kx][co]
// ---------------------------------------------------------------------------
__global__ __launch_bounds__(256) void k_wt(const float* __restrict__ srw, float* __restrict__ wt) {
  int t = blockIdx.x * 256 + threadIdx.x;
  if (t >= 1024 * 64) return;
  int kk = t >> 6, co = t & 63;
  int ci = kk >> 4, r = kk & 15;
  wt[t] = srw[(((size_t)co * 64 + ci) << 4) + r];
}

// ---------------------------------------------------------------------------
// Tiled fp32 GEMM: C[M,N] = A[M,K] @ B[K,N] (+bias)(+add)
// BM=BN=64, BK=16, 256 threads, 4x4 micro-tile. M%64==0, N%64==0, K%16==0.
// ---------------------------------------------------------------------------
__global__ __launch_bounds__(256) void k_gemm(
    const float* __restrict__ A, const float* __restrict__ Bw,
    const float* __restrict__ bias, const float* __restrict__ add,
    float* __restrict__ Cout, int M, int N, int K) {
  __shared__ float sA[16][68];
  __shared__ float sB[16][64];
  int bm = blockIdx.x * 64, bn = blockIdx.y * 64;
  int tid = threadIdx.x;
  int tx = tid & 15, ty = tid >> 4;
  float acc[4][4] = {{0.f}};
  for (int k0 = 0; k0 < K; k0 += 16) {
    int e = tid << 2;
    int am = e >> 4, ak = e & 15;
    float4 a4 = *(const float4*)(A + (size_t)(bm + am) * K + k0 + ak);
    sA[ak + 0][am] = a4.x; sA[ak + 1][am] = a4.y; sA[ak + 2][am] = a4.z; sA[ak + 3][am] = a4.w;
    int bk = e >> 6, nn = e & 63;
    float4 b4 = *(const float4*)(Bw + (size_t)(k0 + bk) * N + bn + nn);
    *(float4*)&sB[bk][nn] = b4;
    __syncthreads();
#pragma unroll
    for (int kk = 0; kk < 16; ++kk) {
      float a[4], bb[4];
#pragma unroll
      for (int i = 0; i < 4; ++i) a[i] = sA[kk][ty * 4 + i];
#pragma unroll
      for (int i = 0; i < 4; ++i) bb[i] = sB[kk][tx * 4 + i];
#pragma unroll
      for (int i = 0; i < 4; ++i)
#pragma unroll
        for (int jj = 0; jj < 4; ++jj) acc[i][jj] += a[i] * bb[jj];
    }
    __syncthreads();
  }
#pragma unroll
  for (int i = 0; i < 4; ++i) {
    int row = bm + ty * 4 + i;
#pragma unroll
    for (int jj = 0; jj < 4; ++jj) {
      int col = bn + tx * 4 + jj;
      float v = acc[i][jj];
      if (bias) v += bias[col];
      if (add) v += add[(size_t)row * N + col];
      Cout[(size_t)row * N + col] = v;
    }
  }
}

// ---------------------------------------------------------------------------
// Fused MLP: out += gelu(xn2 @ W1 + b1) @ W2 + b2   (all fp32, no hidden buf)
// Block = 64 rows; hidden 512 processed in 8 chunks of 64; h tile in LDS.
// ---------------------------------------------------------------------------
__global__ __launch_bounds__(256) void k_mlp(
    const float* __restrict__ A, const float* __restrict__ W1, const float* __restrict__ b1,
    const float* __restrict__ W2, const float* __restrict__ b2, float* __restrict__ out) {
  __shared__ float sA[16][68];
  __shared__ float sW1[16][64];
  __shared__ float sH[64][66];
  __shared__ float sW2[16][128];
  int bm = blockIdx.x * 64;
  int tid = threadIdx.x;
  int tx = tid & 15, ty = tid >> 4;
  float acc2[4][8];
#pragma unroll
  for (int i = 0; i < 4; ++i)
#pragma unroll
    for (int j = 0; j < 8; ++j) acc2[i][j] = 0.f;

  for (int hc = 0; hc < 8; ++hc) {
    float acc1[4][4];
#pragma unroll
    for (int i = 0; i < 4; ++i)
#pragma unroll
      for (int j = 0; j < 4; ++j) acc1[i][j] = 0.f;
    for (int k0 = 0; k0 < 128; k0 += 16) {
      int e = tid << 2;
      int am = e >> 4, ak = e & 15;
      float4 a4 = *(const float4*)(A + (size_t)(bm + am) * 128 + k0 + ak);
      sA[ak + 0][am] = a4.x; sA[ak + 1][am] = a4.y; sA[ak + 2][am] = a4.z; sA[ak + 3][am] = a4.w;
      int bk = e >> 6, nn = e & 63;
      float4 w4 = *(const float4*)(W1 + (size_t)(k0 + bk) * 512 + hc * 64 + nn);
      *(float4*)&sW1[bk][nn] = w4;
      __syncthreads();
#pragma unroll
      for (int kk = 0; kk < 16; ++kk) {
        float a[4], bb[4];
#pragma unroll
        for (int i = 0; i < 4; ++i) a[i] = sA[kk][ty * 4 + i];
#pragma unroll
        for (int i = 0; i < 4; ++i) bb[i] = sW1[kk][tx * 4 + i];
#pragma unroll
        for (int i = 0; i < 4; ++i)
#pragma unroll
          for (int jj = 0; jj < 4; ++jj) acc1[i][jj] += a[i] * bb[jj];
      }
      __syncthreads();
    }
#pragma unroll
    for (int i = 0; i < 4; ++i)
#pragma unroll
      for (int j = 0; j < 4; ++j) {
        float v = acc1[i][j] + b1[hc * 64 + tx * 4 + j];
        sH[ty * 4 + i][tx * 4 + j] = 0.5f * v * (1.f + erff(v * 0.70710678118654752f));
      }
    __syncthreads();
    for (int k0b = 0; k0b < 64; k0b += 16) {
      int e = tid << 3;
      int rw = e >> 7, cl = e & 127;
      float4 w4a = *(const float4*)(W2 + (size_t)(hc * 64 + k0b + rw) * 128 + cl);
      float4 w4b = *(const float4*)(W2 + (size_t)(hc * 64 + k0b + rw) * 128 + cl + 4);
      *(float4*)&sW2[rw][cl] = w4a;
      *(float4*)&sW2[rw][cl + 4] = w4b;
      __syncthreads();
#pragma unroll
      for (int kk = 0; kk < 16; ++kk) {
        float hvals[4], wv[8];
#pragma unroll
        for (int i = 0; i < 4; ++i) hvals[i] = sH[ty * 4 + i][k0b + kk];
#pragma unroll
        for (int j = 0; j < 8; ++j) wv[j] = sW2[kk][tx * 8 + j];
#pragma unroll
        for (int i = 0; i < 4; ++i)
#pragma unroll
          for (int j = 0; j < 8; ++j) acc2[i][j] += hvals[i] * wv[j];
      }
      __syncthreads();
    }
  }
#pragma unroll
  for (int i = 0; i < 4; ++i) {
    int row = bm + ty * 4 + i;
#pragma unroll
    for (int j = 0; j < 8; ++j) {
      int col = tx * 8 + j;
      out[(size_t)row * 128 + col] += acc2[i][j] + b2[col];
    }
  }
}

// ---------------------------------------------------------------------------
// LayerNorm kernels (dim 128 / dim 64), one thread per row
// ---------------------------------------------------------------------------
__global__ __launch_bounds__(256) void k_ln128(const float* __restrict__ in, const float* __restrict__ g,
    const float* __restrict__ bb, float* __restrict__ out, int rows) {
  int t = blockIdx.x * 256 + threadIdx.x;
  if (t >= rows) return;
  const float4* row = (const float4*)(in + (size_t)t * 128);
  float4 v[32];
  float s = 0.f, ss = 0.f;
#pragma unroll
  for (int i = 0; i < 32; ++i) {
    float4 r = row[i]; v[i] = r;
    s += r.x + r.y + r.z + r.w;
    ss += r.x*r.x + r.y*r.y + r.z*r.z + r.w*r.w;
  }
  float m = s * (1.f/128.f);
  float var = ss * (1.f/128.f) - m*m;
  float rs = rsqrtf(var + LN_EPS);
  float4* orow = (float4*)(out + (size_t)t * 128);
#pragma unroll
  for (int i = 0; i < 32; ++i) {
    float4 r = v[i];
    float4 o;
    o.x = (r.x - m) * rs * g[4*i+0] + bb[4*i+0];
    o.y = (r.y - m) * rs * g[4*i+1] + bb[4*i+1];
    o.z = (r.z - m) * rs * g[4*i+2] + bb[4*i+2];
    o.w = (r.w - m) * rs * g[4*i+3] + bb[4*i+3];
    orow[i] = o;
  }
}

__global__ __launch_bounds__(256) void k_ln64(const float* __restrict__ in, const float* __restrict__ g,
    const float* __restrict__ bb, float* __restrict__ out, int rows) {
  int t = blockIdx.x * 256 + threadIdx.x;
  if (t >= rows) return;
  const float4* row = (const float4*)(in + (size_t)t * 64);
  float v[64];
  float s = 0.f, ss = 0.f;
#pragma unroll
  for (int i = 0; i < 16; ++i) {
    float4 r = row[i];
    v[4*i] = r.x; v[4*i+1] = r.y; v[4*i+2] = r.z; v[4*i+3] = r.w;
    s += r.x + r.y + r.z + r.w;
    ss += r.x*r.x + r.y*r.y + r.z*r.z + r.w*r.w;
  }
  float m = s * (1.f/64.f);
  float var = ss * (1.f/64.f) - m*m;
  float rs = rsqrtf(var + LN_EPS);
#pragma unroll
  for (int i = 0; i < 64; ++i)
    out[(size_t)t * 64 + i] = (v[i] - m) * rs * g[i] + bb[i];
}

// ---------------------------------------------------------------------------
// K7: attention, two-phase (K then V through the same f32 LDS buffer).
// grid = B * 2 heads * 14 query-chunks of 64.
// ---------------------------------------------------------------------------
__global__ __launch_bounds__(256) void k_attn(const float* __restrict__ q, const float* __restrict__ kg,
    const float* __restrict__ vg, float* __restrict__ o) {
  __shared__ float KV[NS * 66];
  int blk = blockIdx.x;
  int chunk = blk % 14;
  int bh = blk / 14;
  int h = bh & 1, b = bh >> 1;
  int tid = threadIdx.x;
  int w = tid >> 6, lane = tid & 63;
  const float* kb = kg + (size_t)b * NS * 128 + h * 64;
  const float* vb = vg + (size_t)b * NS * 128 + h * 64;
  const float scale = 0.17677669529663687f;  // 32^-0.5
  for (int e = tid; e < NS * 64; e += 256)
    KV[(e >> 6) * 66 + (e & 63)] = kb[(size_t)(e >> 6) * 128 + (e & 63)];
  __syncthreads();
  float pn[16][4];
#pragma unroll
  for (int s = 0; s < 16; ++s) {
    int qi = chunk * 64 + s * 4 + w;
    if (qi >= ND) continue;                 // wave-uniform
    const float* qr = q + ((size_t)b * ND + qi) * 128 + h * 64;
    float qreg[64];
#pragma unroll
    for (int d = 0; d < 16; ++d) {
      float4 r = ((const float4*)qr)[d];
      qreg[4*d] = r.x; qreg[4*d+1] = r.y; qreg[4*d+2] = r.z; qreg[4*d+3] = r.w;
    }
    float ps[4];
    ps[0] = ps[1] = ps[2] = ps[3] = -1e30f;
#pragma unroll
    for (int tk = 0; tk < 3; ++tk) {
      int j = tk * 64 + lane;
      float dot = 0.f;
#pragma unroll
      for (int d = 0; d < 64; ++d) dot += qreg[d] * KV[j * 66 + d];
      ps[tk] = dot * scale;
    }
    if (lane < 4) {
      int j = 192 + lane;
      float dot = 0.f;
#pragma unroll
      for (int d = 0; d < 64; ++d) dot += qreg[d] * KV[j * 66 + d];
      ps[3] = dot * scale;
    }
    float mx = fmaxf(fmaxf(ps[0], ps[1]), fmaxf(ps[2], ps[3]));
#pragma unroll
    for (int mm = 32; mm > 0; mm >>= 1) mx = fmaxf(mx, __shfl_xor(mx, mm));
    float e0 = expf(ps[0] - mx), e1 = expf(ps[1] - mx);
    float e2 = expf(ps[2] - mx), e3 = expf(ps[3] - mx);
    float sum = e0 + e1 + e2 + e3;
#pragma unroll
    for (int mm = 32; mm > 0; mm >>= 1) sum += __shfl_xor(sum, mm);
    float inv = 1.f / sum;
    pn[s][0] = e0 * inv; pn[s][1] = e1 * inv; pn[s][2] = e2 * inv; pn[s][3] = e3 * inv;
  }
  __syncthreads();
  for (int e = tid; e < NS * 64; e += 256)
    KV[(e >> 6) * 66 + (e & 63)] = vb[(size_t)(e >> 6) * 128 + (e & 63)];
  __syncthreads();
#pragma unroll
  for (int s = 0; s < 16; ++s) {
    int qi = chunk * 64 + s * 4 + w;
    if (qi >= ND) continue;                 // wave-uniform
    float oacc = 0.f;
#pragma unroll
    for (int tk = 0; tk < 3; ++tk) {
#pragma unroll 16
      for (int jj = 0; jj < 64; ++jj) {
        float pj = __shfl(pn[s][tk], jj);
        oacc += pj * KV[(tk * 64 + jj) * 66 + lane];
      }
    }
#pragma unroll
    for (int jj = 0; jj < 4; ++jj) {
      float pj = __shfl(pn[s][3], jj);
      oacc += pj * KV[(192 + jj) * 66 + lane];
    }
    o[((size_t)b * ND + qi) * 128 + h * 64 + lane] = oacc;
  }
}

// ---------------------------------------------------------------------------
// K8: bilinear grid-sample of pos_embed at pos_down, accumulate into out
// ---------------------------------------------------------------------------
__global__ __launch_bounds__(256) void k_posfeat(const float* __restrict__ pd,
    const float* __restrict__ pe, float* __restrict__ out) {
  int t = blockIdx.x * 256 + threadIdx.x;
  int row = t >> 5, lane = t & 31;
  if (row >= B_ * ND) return;
  float gx = pd[(size_t)2*row] * 2.f - 1.f;
  float gy = pd[(size_t)2*row+1] * 2.f - 1.f;
  float ix = ((gx + 1.f) * 56.f - 1.f) * 0.5f;
  float iy = ((gy + 1.f) * 56.f - 1.f) * 0.5f;
  float x0 = floorf(ix), y0 = floorf(iy);
  float wx1 = ix - x0, wy1 = iy - y0;
  float wx0 = 1.f - wx1, wy0 = 1.f - wy1;
  float4 acc = make_float4(0.f, 0.f, 0.f, 0.f);
#pragma unroll
  for (int cy = 0; cy < 2; ++cy) {
#pragma unroll
    for (int cx = 0; cx < 2; ++cx) {
      float xc = x0 + (float)cx, yc = y0 + (float)cy;
      float wgt = (cx ? wx1 : wx0) * (cy ? wy1 : wy0);
      bool valid = (xc >= 0.f) && (xc < 56.f) && (yc >= 0.f) && (yc < 56.f);
      if (valid) {
        int lin = (int)yc * 56 + (int)xc;
        float4 pv = ((const float4*)(pe + (size_t)lin * 128))[lane];
        acc.x += wgt * pv.x; acc.y += wgt * pv.y;
        acc.z += wgt * pv.z; acc.w += wgt * pv.w;
      }
    }
  }
  float4* op = (float4*)(out + (size_t)row * 128) + lane;
  float4 cur = *op;
  cur.x += acc.x; cur.y += acc.y; cur.z += acc.z; cur.w += acc.w;
  *op = cur;
}

// ---------------------------------------------------------------------------
// launcher
// ---------------------------------------------------------------------------
extern "C" void kernel_launch(void* const* d_in, const int* in_sizes, int n_in,
                              void* d_out, int out_size, void* d_ws, size_t ws_size,
                              hipStream_t stream) {
  const float* x      = (const float*)d_in[0];
  const float* pos    = (const float*)d_in[1];
  const float* pe     = (const float*)d_in[2];
  const float* nu     = (const float*)d_in[3];
  const float* norm_g = (const float*)d_in[4];
  const float* norm_b = (const float*)d_in[5];
  const float* conf_w = (const float*)d_in[6];
  const float* conf_b = (const float*)d_in[7];
  const float* n1g    = (const float*)d_in[8];
  const float* n1b    = (const float*)d_in[9];
  const float* q_w    = (const float*)d_in[10];
  const float* k_w    = (const float*)d_in[11];
  const float* v_w    = (const float*)d_in[12];
  const float* proj_w = (const float*)d_in[13];
  const float* proj_b = (const float*)d_in[14];
  const float* sr_w   = (const float*)d_in[15];
  const float* sr_b   = (const float*)d_in[16];
  const float* srn_g  = (const float*)d_in[17];
  const float* srn_b  = (const float*)d_in[18];
  const float* fc_w   = (const float*)d_in[19];
  const float* fc_b   = (const float*)d_in[20];
  const float* n2g    = (const float*)d_in[21];
  const float* n2b    = (const float*)d_in[22];
  const float* fc1_w  = (const float*)d_in[23];
  const float* fc1_b  = (const float*)d_in[24];
  const float* fc2_w  = (const float*)d_in[25];
  const float* fc2_b  = (const float*)d_in[26];

  char* ws = (char*)d_ws;
  // workspace layout (bytes); total 190,578,688
  // ROUND-3 BUGFIX: S truly needs B*HW*65*4 = 52,183,040 B (was shorted to
  // 52,166,656 -> P overlapped S's tail -> race in k_filter for batch 63).
  // P now aliases qb/ob (P live only filter->conv; qb first written at
  // q-GEMM, which is after conv). S gets the big region exclusively.
  double*         scores = (double*)(ws + 0);                //  1,580,544
  int*            idx    = (int*)(ws + 1605632);             //    200,704
  float*          xd     = (float*)(ws + 1835008);           // 13,647,872
  float*          xn     = (float*)(ws + 15728640);          // 13,647,872
  float*          pd     = (float*)(ws + 29491200);          //    426,496
  float*          qb     = (float*)(ws + 30408704);          // 27,295,744; P alias; later O2
  float*          ob     = (float*)(ws + 58720256);          // 27,295,744; P tail alias; later xn2
  float*          wt     = (float*)(ws + 86507520);          //    262,144
  char*           big    = ws + 87031808;                    // 103,546,880 region
  float*          S      = (float*)big;                      // 52,183,040 (exclusive; dead after filter)
  float*          P      = (float*)(ws + 30408704);          // 51,380,224 (alias qb..ob; dead after conv)
  float*          xs_c   = (float*)big;                      //  3,211,264 (reuses S after filter)
  float*          xs_n   = (float*)(big + 3211264);          //  3,211,264
  float*          kbuf   = (float*)(big + 6422528);          //  6,422,528
  float*          vbuf   = (float*)(big + 12845056);         //  6,422,528
  float*          O2     = qb;
  float*          xn2    = ob;
  float*          out    = (float*)d_out;

  // 1) f64 conf+gumbel scores
  k_conf<<<(B_ * N_) / 256, 256, 0, stream>>>(x, norm_g, norm_b, conf_w, conf_b, nu, scores);
  // 2) top-784 per batch (f64 keys)
  k_topk<<<B_, 256, 0, stream>>>(scores, idx);
  // 3) gather + LN(norm1)
  k_gather_ln<<<(B_ * ND + 255) / 256, 256, 0, stream>>>(x, pos, idx, n1g, n1b, xd, xn, pd);
  // 4) token2map scatter (inline LN, f64 binning)
  hipMemsetAsync(S, 0, (size_t)B_ * HW * 65 * sizeof(float), stream);
  k_scatter<<<(B_ * N_) / 256, 256, 0, stream>>>(x, n1g, n1b, pos, S);
  // 5) normalize + gaussian reconstruct -> patch layout (f32)
  k_filter<<<(B_ * HW) / 256, 256, 0, stream>>>(S, P);
  // 6) conv weights transpose, conv-as-GEMM, srnorm
  k_wt<<<(1024 * 64) / 256, 256, 0, stream>>>(sr_w, wt);
  dim3 g_conv(NS * B_ / 64, 1);
  k_gemm<<<g_conv, 256, 0, stream>>>(P, wt, sr_b, nullptr, xs_c, B_ * NS, 64, 1024);
  k_ln64<<<(B_ * NS + 255) / 256, 256, 0, stream>>>(xs_c, srn_g, srn_b, xs_n, B_ * NS);
  // 7) k, v, q projections (q GEMM overwrites P region -- P is dead by now)
  dim3 g_kv(B_ * NS / 64, 2);
  k_gemm<<<g_kv, 256, 0, stream>>>(xs_n, k_w, nullptr, nullptr, kbuf, B_ * NS, 128, 64);
  k_gemm<<<g_kv, 256, 0, stream>>>(xs_n, v_w, nullptr, nullptr, vbuf, B_ * NS, 128, 64);
  dim3 g_row(B_ * ND / 64, 2);
  k_gemm<<<g_row, 256, 0, stream>>>(xn, q_w, nullptr, nullptr, qb, B_ * ND, 128, 64);
  // 8) attention (two-phase f32)
  k_attn<<<B_ * 2 * 14, 256, 0, stream>>>(qb, kbuf, vbuf, ob);
  // 9) x2 = x_down@fc_w + fc_b + (o@proj_w + proj_b)  -> d_out
  k_gemm<<<g_row, 256, 0, stream>>>(ob, proj_w, proj_b, nullptr, O2, B_ * ND, 128, 128);
  k_gemm<<<g_row, 256, 0, stream>>>(xd, fc_w, fc_b, O2, out, B_ * ND, 128, 64);
  // 10) fused MLP: out += gelu(LN(out)@fc1)@fc2
  k_ln128<<<(B_ * ND + 255) / 256, 256, 0, stream>>>(out, n2g, n2b, xn2, B_ * ND);
  k_mlp<<<B_ * ND / 64, 256, 0, stream>>>(xn2, fc1_w, fc1_b, fc2_w, fc2_b, out);
  // 11) + pos_feat (bilinear grid sample)
  k_posfeat<<<(B_ * ND * 32) / 256, 256, 0, stream>>>(pd, pe, out);
}

// Round 5
// 1666.825 us; speedup vs baseline: 1.3503x; 1.3503x over previous
//
#include <hip/hip_runtime.h>
#include <math.h>

#define DEVINL __device__ __forceinline__

constexpr int B_ = 64;
constexpr int N_ = 3136;
constexpr int C_ = 64;        // DIM
constexpr int NG = 49;        // N_grid
constexpr int NSAMP = 784;    // SAMPLE_NUM
constexpr int ND = NG + NSAMP;     // 833
constexpr int NREST = N_ - NG;     // 3087
constexpr int H_ = 56, W_ = 56;
constexpr int HW = H_ * W_;        // 3136
constexpr int NS = 14 * 14;        // 196 tokens after strided conv
constexpr float LN_EPS = 1e-5f;
constexpr float EPS6 = 1e-6f;

// ---------------------------------------------------------------------------
// K1: conf scores in FP64 (discrete top-k decision must match f64 np ref)
// ---------------------------------------------------------------------------
__global__ __launch_bounds__(256) void k_conf(
    const float* __restrict__ x, const float* __restrict__ ng, const float* __restrict__ nb,
    const float* __restrict__ cw, const float* __restrict__ cb,
    const float* __restrict__ nu, double* __restrict__ scores) {
  int t = blockIdx.x * 256 + threadIdx.x;
  if (t >= B_ * N_) return;
  int b = t / N_, n = t - b * N_;
  if (n < NG) return;
  const float4* row = (const float4*)(x + (size_t)t * C_);
  float v[C_];
#pragma unroll
  for (int i = 0; i < 16; ++i) {
    float4 r = row[i];
    v[4*i] = r.x; v[4*i+1] = r.y; v[4*i+2] = r.z; v[4*i+3] = r.w;
  }
  double sd = 0.0;
#pragma unroll
  for (int i = 0; i < C_; ++i) sd += (double)v[i];
  double md = sd * (1.0/64.0);
  double vd = 0.0;
#pragma unroll
  for (int i = 0; i < C_; ++i) { double d = (double)v[i] - md; vd += d * d; }
  vd *= (1.0/64.0);
  double rsd = 1.0 / sqrt(vd + 1e-5);
  double conf = (double)cb[0];
#pragma unroll
  for (int i = 0; i < C_; ++i) {
    double xnv = ((double)v[i] - md) * rsd;
    conf += (xnv * (double)ng[i] + (double)nb[i]) * (double)cw[i];
  }
  double u = (double)nu[(size_t)b * NREST + (n - NG)];
  double noise = -log(-log(u + 1e-6) + 1e-6);
  scores[(size_t)b * NREST + (n - NG)] = conf + noise;
}

// ---------------------------------------------------------------------------
// K2: per-batch top-784 of 3087 via bitonic sort of (f64-key, idx) in LDS.
// Descending score, ties -> lower idx (matches jax.lax.top_k).
// ---------------------------------------------------------------------------
__global__ __launch_bounds__(256) void k_topk(const double* __restrict__ scores, int* __restrict__ idx) {
  __shared__ unsigned long long ks[4096];
  __shared__ unsigned int is_[4096];
  int b = blockIdx.x;
  int tid = threadIdx.x;
  const double* sc = scores + (size_t)b * NREST;
  for (int i = tid; i < 4096; i += 256) {
    if (i < NREST) {
      long long bits = __double_as_longlong(sc[i]);
      unsigned long long ub = (unsigned long long)bits;
      ub = (bits < 0) ? ~ub : (ub | 0x8000000000000000ULL);  // monotone map
      ks[i] = ~ub;               // ascending key == descending score
      is_[i] = (unsigned int)i;
    } else {
      ks[i] = 0xFFFFFFFFFFFFFFFFULL;
      is_[i] = 0xFFFFFFFFu;
    }
  }
  __syncthreads();
  for (int k = 2; k <= 4096; k <<= 1) {
    for (int j = k >> 1; j > 0; j >>= 1) {
      for (int i = tid; i < 4096; i += 256) {
        int l = i ^ j;
        if (l > i) {
          unsigned long long ka = ks[i], kc = ks[l];
          unsigned int ia = is_[i], ic = is_[l];
          bool agtc = (ka > kc) || (ka == kc && ia > ic);
          bool up = ((i & k) == 0);
          if (up == agtc) { ks[i] = kc; ks[l] = ka; is_[i] = ic; is_[l] = ia; }
        }
      }
      __syncthreads();
    }
  }
  for (int r = tid; r < NSAMP; r += 256)
    idx[(size_t)b * NSAMP + r] = (int)is_[r];
}

// ---------------------------------------------------------------------------
// K3: gather x_down/pos_down rows; LayerNorm(x_down, norm1) -> xn
// ---------------------------------------------------------------------------
__global__ __launch_bounds__(256) void k_gather_ln(
    const float* __restrict__ x, const float* __restrict__ pos, const int* __restrict__ idx,
    const float* __restrict__ n1g, const float* __restrict__ n1b,
    float* __restrict__ xd, float* __restrict__ xn, float* __restrict__ pd) {
  int t = blockIdx.x * 256 + threadIdx.x;
  if (t >= B_ * ND) return;
  int b = t / ND, r = t - b * ND;
  int srcn = (r < NG) ? r : (NG + idx[(size_t)b * NSAMP + (r - NG)]);
  const float4* row = (const float4*)(x + ((size_t)b * N_ + srcn) * C_);
  float4* xdr = (float4*)(xd + (size_t)t * C_);
  float v[C_];
  float s = 0.f, ss = 0.f;
#pragma unroll
  for (int i = 0; i < 16; ++i) {
    float4 rr = row[i];
    xdr[i] = rr;
    v[4*i] = rr.x; v[4*i+1] = rr.y; v[4*i+2] = rr.z; v[4*i+3] = rr.w;
    s += rr.x + rr.y + rr.z + rr.w;
    ss += rr.x*rr.x + rr.y*rr.y + rr.z*rr.z + rr.w*rr.w;
  }
  float m = s * (1.f/64.f);
  float var = ss * (1.f/64.f) - m*m;
  float rs = rsqrtf(var + LN_EPS);
#pragma unroll
  for (int i = 0; i < C_; ++i)
    xn[(size_t)t * C_ + i] = (v[i] - m) * rs * n1g[i] + n1b[i];
  pd[(size_t)2*t]   = pos[((size_t)b * N_ + srcn) * 2];
  pd[(size_t)2*t+1] = pos[((size_t)b * N_ + srcn) * 2 + 1];
}

// ---------------------------------------------------------------------------
// K4: scatter (ROUND-4 REWRITE): one WAVE per token, lane = channel.
// Wave-shuffle LN reduction; each lane does ONE coalesced atomicAdd into the
// token's bin (64 contiguous floats -> 4-5 cache lines/token instead of
// 65 serialized uncoalesced atomics/thread). f64 bin assignment kept.
// ---------------------------------------------------------------------------
__global__ __launch_bounds__(256) void k_scatter(
    const float* __restrict__ x, const float* __restrict__ n1g, const float* __restrict__ n1b,
    const float* __restrict__ pos, float* __restrict__ S) {
  int gt = blockIdx.x * 256 + threadIdx.x;
  int tok = gt >> 6, lane = gt & 63;
  if (tok >= B_ * N_) return;
  int b = tok / N_;
  float v = x[(size_t)tok * C_ + lane];
  float s = v, ss = v * v;
#pragma unroll
  for (int m = 32; m > 0; m >>= 1) {
    s += __shfl_xor(s, m);
    ss += __shfl_xor(ss, m);
  }
  float mean = s * (1.f/64.f);
  float var = ss * (1.f/64.f) - mean * mean;
  float rs = rsqrtf(var + LN_EPS);
  double px = fmin(fmax((double)pos[(size_t)2*tok],   0.0), 1.0) * (double)(W_ - 1);
  double py = fmin(fmax((double)pos[(size_t)2*tok+1], 0.0), 1.0) * (double)(H_ - 1);
  int xi = (int)rint(px), yi = (int)rint(py);
  float* base = S + ((size_t)b * HW + yi * W_ + xi) * 65;
  atomicAdd(base + lane, (v - mean) * rs * n1g[lane] + n1b[lane]);
  if (lane == 0) atomicAdd(base + 64, 1.f);
}

// ---------------------------------------------------------------------------
// K5: normalize + masked 3x3 gaussian reconstruct -> conv-patch layout (f32)
// P[b*196+j][ci*16+ky*4+kx]
// ---------------------------------------------------------------------------
__global__ __launch_bounds__(256) void k_filter(const float* __restrict__ S, float* __restrict__ P) {
  int t = blockIdx.x * 256 + threadIdx.x;
  if (t >= B_ * HW) return;
  int b = t / HW, p = t - b * HW;
  int y = p / W_, x = p - y * W_;
  const float* Sb = S + (size_t)b * HW * 65;
  const float e1 = 0.882496902584595f;   // exp(-1/8)
  const float e2 = 0.778800783071405f;   // exp(-1/4)
  const float Z = 1.f + 4.f * (e1 + e2);
  float m0 = Sb[(size_t)p * 65 + 64];
  float mb0 = m0 > 0.f ? 1.f : 0.f;
  float cfac = mb0 / (m0 + EPS6);
  float scale[9];
  int off[9];
  float mi = 0.f;
  int kk = 0;
#pragma unroll
  for (int dy = -1; dy <= 1; ++dy) {
#pragma unroll
    for (int dx = -1; dx <= 1; ++dx) {
      int ny = y + dy, nx = x + dx;
      float w = ((dx == 0 && dy == 0) ? 1.f : ((dx*dx + dy*dy) == 1 ? e1 : e2)) / Z;
      bool in = (ny >= 0 && ny < H_ && nx >= 0 && nx < W_);
      int np = in ? (ny * W_ + nx) : p;
      float mm = in ? Sb[(size_t)np * 65 + 64] : 0.f;
      float mb = mm > 0.f ? 1.f : 0.f;
      mi += w * mb;
      scale[kk] = in ? (w * mb / (mm + EPS6)) : 0.f;
      off[kk] = np * 65;
      ++kk;
    }
  }
  float inv_mi = (mi > 0.f ? 1.f : 0.f) / (mi + EPS6);
  float outer = (1.f - mb0) * inv_mi;
  int j = (y >> 2) * 14 + (x >> 2);
  int colb = (y & 3) * 4 + (x & 3);
  float* Pr = P + ((size_t)b * NS + j) * 1024 + colb;
  size_t pc = (size_t)p * 65;
  for (int c = 0; c < C_; ++c) {
    float fs = 0.f;
#pragma unroll
    for (int q = 0; q < 9; ++q) fs += scale[q] * Sb[(size_t)off[q] + c];
    Pr[c * 16] = Sb[pc + c] * cfac + outer * fs;
  }
}

// ---------------------------------------------------------------------------
// K6: transpose sr_w (co,ci,ky,kx) -> w_t[kk=ci*16+ky*4+kx][co]
// ---------------------------------------------------------------------------
__global__ __launch_bounds__(256) void k_wt(const float* __restrict__ srw, float* __restrict__ wt) {
  int t = blockIdx.x * 256 + threadIdx.x;
  if (t >= 1024 * 64) return;
  int kk = t >> 6, co = t & 63;
  int ci = kk >> 4, r = kk & 15;
  wt[t] = srw[(((size_t)co * 64 + ci) << 4) + r];
}

// ---------------------------------------------------------------------------
// Tiled fp32 GEMM: C[M,N] = A[M,K] @ B[K,N] (+bias)(+add)
// BM=BN=64, BK=16, 256 threads, 4x4 micro-tile. M%64==0, N%64==0, K%16==0.
// ---------------------------------------------------------------------------
__global__ __launch_bounds__(256) void k_gemm(
    const float* __restrict__ A, const float* __restrict__ Bw,
    const float* __restrict__ bias, const float* __restrict__ add,
    float* __restrict__ Cout, int M, int N, int K) {
  __shared__ float sA[16][68];
  __shared__ float sB[16][64];
  int bm = blockIdx.x * 64, bn = blockIdx.y * 64;
  int tid = threadIdx.x;
  int tx = tid & 15, ty = tid >> 4;
  float acc[4][4] = {{0.f}};
  for (int k0 = 0; k0 < K; k0 += 16) {
    int e = tid << 2;
    int am = e >> 4, ak = e & 15;
    float4 a4 = *(const float4*)(A + (size_t)(bm + am) * K + k0 + ak);
    sA[ak + 0][am] = a4.x; sA[ak + 1][am] = a4.y; sA[ak + 2][am] = a4.z; sA[ak + 3][am] = a4.w;
    int bk = e >> 6, nn = e & 63;
    float4 b4 = *(const float4*)(Bw + (size_t)(k0 + bk) * N + bn + nn);
    *(float4*)&sB[bk][nn] = b4;
    __syncthreads();
#pragma unroll
    for (int kk = 0; kk < 16; ++kk) {
      float a[4], bb[4];
#pragma unroll
      for (int i = 0; i < 4; ++i) a[i] = sA[kk][ty * 4 + i];
#pragma unroll
      for (int i = 0; i < 4; ++i) bb[i] = sB[kk][tx * 4 + i];
#pragma unroll
      for (int i = 0; i < 4; ++i)
#pragma unroll
        for (int jj = 0; jj < 4; ++jj) acc[i][jj] += a[i] * bb[jj];
    }
    __syncthreads();
  }
#pragma unroll
  for (int i = 0; i < 4; ++i) {
    int row = bm + ty * 4 + i;
#pragma unroll
    for (int jj = 0; jj < 4; ++jj) {
      int col = bn + tx * 4 + jj;
      float v = acc[i][jj];
      if (bias) v += bias[col];
      if (add) v += add[(size_t)row * N + col];
      Cout[(size_t)row * N + col] = v;
    }
  }
}

// ---------------------------------------------------------------------------
// Fused MLP: out += gelu(xn2 @ W1 + b1) @ W2 + b2   (all fp32, no hidden buf)
// ---------------------------------------------------------------------------
__global__ __launch_bounds__(256) void k_mlp(
    const float* __restrict__ A, const float* __restrict__ W1, const float* __restrict__ b1,
    const float* __restrict__ W2, const float* __restrict__ b2, float* __restrict__ out) {
  __shared__ float sA[16][68];
  __shared__ float sW1[16][64];
  __shared__ float sH[64][66];
  __shared__ float sW2[16][128];
  int bm = blockIdx.x * 64;
  int tid = threadIdx.x;
  int tx = tid & 15, ty = tid >> 4;
  float acc2[4][8];
#pragma unroll
  for (int i = 0; i < 4; ++i)
#pragma unroll
    for (int j = 0; j < 8; ++j) acc2[i][j] = 0.f;

  for (int hc = 0; hc < 8; ++hc) {
    float acc1[4][4];
#pragma unroll
    for (int i = 0; i < 4; ++i)
#pragma unroll
      for (int j = 0; j < 4; ++j) acc1[i][j] = 0.f;
    for (int k0 = 0; k0 < 128; k0 += 16) {
      int e = tid << 2;
      int am = e >> 4, ak = e & 15;
      float4 a4 = *(const float4*)(A + (size_t)(bm + am) * 128 + k0 + ak);
      sA[ak + 0][am] = a4.x; sA[ak + 1][am] = a4.y; sA[ak + 2][am] = a4.z; sA[ak + 3][am] = a4.w;
      int bk = e >> 6, nn = e & 63;
      float4 w4 = *(const float4*)(W1 + (size_t)(k0 + bk) * 512 + hc * 64 + nn);
      *(float4*)&sW1[bk][nn] = w4;
      __syncthreads();
#pragma unroll
      for (int kk = 0; kk < 16; ++kk) {
        float a[4], bb[4];
#pragma unroll
        for (int i = 0; i < 4; ++i) a[i] = sA[kk][ty * 4 + i];
#pragma unroll
        for (int i = 0; i < 4; ++i) bb[i] = sW1[kk][tx * 4 + i];
#pragma unroll
        for (int i = 0; i < 4; ++i)
#pragma unroll
          for (int jj = 0; jj < 4; ++jj) acc1[i][jj] += a[i] * bb[jj];
      }
      __syncthreads();
    }
#pragma unroll
    for (int i = 0; i < 4; ++i)
#pragma unroll
      for (int j = 0; j < 4; ++j) {
        float v = acc1[i][j] + b1[hc * 64 + tx * 4 + j];
        sH[ty * 4 + i][tx * 4 + j] = 0.5f * v * (1.f + erff(v * 0.70710678118654752f));
      }
    __syncthreads();
    for (int k0b = 0; k0b < 64; k0b += 16) {
      int e = tid << 3;
      int rw = e >> 7, cl = e & 127;
      float4 w4a = *(const float4*)(W2 + (size_t)(hc * 64 + k0b + rw) * 128 + cl);
      float4 w4b = *(const float4*)(W2 + (size_t)(hc * 64 + k0b + rw) * 128 + cl + 4);
      *(float4*)&sW2[rw][cl] = w4a;
      *(float4*)&sW2[rw][cl + 4] = w4b;
      __syncthreads();
#pragma unroll
      for (int kk = 0; kk < 16; ++kk) {
        float hvals[4], wv[8];
#pragma unroll
        for (int i = 0; i < 4; ++i) hvals[i] = sH[ty * 4 + i][k0b + kk];
#pragma unroll
        for (int j = 0; j < 8; ++j) wv[j] = sW2[kk][tx * 8 + j];
#pragma unroll
        for (int i = 0; i < 4; ++i)
#pragma unroll
          for (int j = 0; j < 8; ++j) acc2[i][j] += hvals[i] * wv[j];
      }
      __syncthreads();
    }
  }
#pragma unroll
  for (int i = 0; i < 4; ++i) {
    int row = bm + ty * 4 + i;
#pragma unroll
    for (int j = 0; j < 8; ++j) {
      int col = tx * 8 + j;
      out[(size_t)row * 128 + col] += acc2[i][j] + b2[col];
    }
  }
}

// ---------------------------------------------------------------------------
// LayerNorm kernels (dim 128 / dim 64), one thread per row
// ---------------------------------------------------------------------------
__global__ __launch_bounds__(256) void k_ln128(const float* __restrict__ in, const float* __restrict__ g,
    const float* __restrict__ bb, float* __restrict__ out, int rows) {
  int t = blockIdx.x * 256 + threadIdx.x;
  if (t >= rows) return;
  const float4* row = (const float4*)(in + (size_t)t * 128);
  float4 v[32];
  float s = 0.f, ss = 0.f;
#pragma unroll
  for (int i = 0; i < 32; ++i) {
    float4 r = row[i]; v[i] = r;
    s += r.x + r.y + r.z + r.w;
    ss += r.x*r.x + r.y*r.y + r.z*r.z + r.w*r.w;
  }
  float m = s * (1.f/128.f);
  float var = ss * (1.f/128.f) - m*m;
  float rs = rsqrtf(var + LN_EPS);
  float4* orow = (float4*)(out + (size_t)t * 128);
#pragma unroll
  for (int i = 0; i < 32; ++i) {
    float4 r = v[i];
    float4 o;
    o.x = (r.x - m) * rs * g[4*i+0] + bb[4*i+0];
    o.y = (r.y - m) * rs * g[4*i+1] + bb[4*i+1];
    o.z = (r.z - m) * rs * g[4*i+2] + bb[4*i+2];
    o.w = (r.w - m) * rs * g[4*i+3] + bb[4*i+3];
    orow[i] = o;
  }
}

__global__ __launch_bounds__(256) void k_ln64(const float* __restrict__ in, const float* __restrict__ g,
    const float* __restrict__ bb, float* __restrict__ out, int rows) {
  int t = blockIdx.x * 256 + threadIdx.x;
  if (t >= rows) return;
  const float4* row = (const float4*)(in + (size_t)t * 64);
  float v[64];
  float s = 0.f, ss = 0.f;
#pragma unroll
  for (int i = 0; i < 16; ++i) {
    float4 r = row[i];
    v[4*i] = r.x; v[4*i+1] = r.y; v[4*i+2] = r.z; v[4*i+3] = r.w;
    s += r.x + r.y + r.z + r.w;
    ss += r.x*r.x + r.y*r.y + r.z*r.z + r.w*r.w;
  }
  float m = s * (1.f/64.f);
  float var = ss * (1.f/64.f) - m*m;
  float rs = rsqrtf(var + LN_EPS);
#pragma unroll
  for (int i = 0; i < 64; ++i)
    out[(size_t)t * 64 + i] = (v[i] - m) * rs * g[i] + bb[i];
}

// ---------------------------------------------------------------------------
// K7: attention, two-phase (K then V through the same f32 LDS buffer).
// grid = B * 2 heads * 14 query-chunks of 64.
// ---------------------------------------------------------------------------
__global__ __launch_bounds__(256) void k_attn(const float* __restrict__ q, const float* __restrict__ kg,
    const float* __restrict__ vg, float* __restrict__ o) {
  __shared__ float KV[NS * 66];
  int blk = blockIdx.x;
  int chunk = blk % 14;
  int bh = blk / 14;
  int h = bh & 1, b = bh >> 1;
  int tid = threadIdx.x;
  int w = tid >> 6, lane = tid & 63;
  const float* kb = kg + (size_t)b * NS * 128 + h * 64;
  const float* vb = vg + (size_t)b * NS * 128 + h * 64;
  const float scale = 0.17677669529663687f;  // 32^-0.5
  for (int e = tid; e < NS * 64; e += 256)
    KV[(e >> 6) * 66 + (e & 63)] = kb[(size_t)(e >> 6) * 128 + (e & 63)];
  __syncthreads();
  float pn[16][4];
#pragma unroll
  for (int s = 0; s < 16; ++s) {
    int qi = chunk * 64 + s * 4 + w;
    if (qi >= ND) continue;                 // wave-uniform
    const float* qr = q + ((size_t)b * ND + qi) * 128 + h * 64;
    float qreg[64];
#pragma unroll
    for (int d = 0; d < 16; ++d) {
      float4 r = ((const float4*)qr)[d];
      qreg[4*d] = r.x; qreg[4*d+1] = r.y; qreg[4*d+2] = r.z; qreg[4*d+3] = r.w;
    }
    float ps[4];
    ps[0] = ps[1] = ps[2] = ps[3] = -1e30f;
#pragma unroll
    for (int tk = 0; tk < 3; ++tk) {
      int j = tk * 64 + lane;
      float dot = 0.f;
#pragma unroll
      for (int d = 0; d < 64; ++d) dot += qreg[d] * KV[j * 66 + d];
      ps[tk] = dot * scale;
    }
    if (lane < 4) {
      int j = 192 + lane;
      float dot = 0.f;
#pragma unroll
      for (int d = 0; d < 64; ++d) dot += qreg[d] * KV[j * 66 + d];
      ps[3] = dot * scale;
    }
    float mx = fmaxf(fmaxf(ps[0], ps[1]), fmaxf(ps[2], ps[3]));
#pragma unroll
    for (int mm = 32; mm > 0; mm >>= 1) mx = fmaxf(mx, __shfl_xor(mx, mm));
    float e0 = expf(ps[0] - mx), e1 = expf(ps[1] - mx);
    float e2 = expf(ps[2] - mx), e3 = expf(ps[3] - mx);
    float sum = e0 + e1 + e2 + e3;
#pragma unroll
    for (int mm = 32; mm > 0; mm >>= 1) sum += __shfl_xor(sum, mm);
    float inv = 1.f / sum;
    pn[s][0] = e0 * inv; pn[s][1] = e1 * inv; pn[s][2] = e2 * inv; pn[s][3] = e3 * inv;
  }
  __syncthreads();
  for (int e = tid; e < NS * 64; e += 256)
    KV[(e >> 6) * 66 + (e & 63)] = vb[(size_t)(e >> 6) * 128 + (e & 63)];
  __syncthreads();
#pragma unroll
  for (int s = 0; s < 16; ++s) {
    int qi = chunk * 64 + s * 4 + w;
    if (qi >= ND) continue;                 // wave-uniform
    float oacc = 0.f;
#pragma unroll
    for (int tk = 0; tk < 3; ++tk) {
#pragma unroll 16
      for (int jj = 0; jj < 64; ++jj) {
        float pj = __shfl(pn[s][tk], jj);
        oacc += pj * KV[(tk * 64 + jj) * 66 + lane];
      }
    }
#pragma unroll
    for (int jj = 0; jj < 4; ++jj) {
      float pj = __shfl(pn[s][3], jj);
      oacc += pj * KV[(192 + jj) * 66 + lane];
    }
    o[((size_t)b * ND + qi) * 128 + h * 64 + lane] = oacc;
  }
}

// ---------------------------------------------------------------------------
// K8: bilinear grid-sample of pos_embed at pos_down, accumulate into out
// ---------------------------------------------------------------------------
__global__ __launch_bounds__(256) void k_posfeat(const float* __restrict__ pd,
    const float* __restrict__ pe, float* __restrict__ out) {
  int t = blockIdx.x * 256 + threadIdx.x;
  int row = t >> 5, lane = t & 31;
  if (row >= B_ * ND) return;
  float gx = pd[(size_t)2*row] * 2.f - 1.f;
  float gy = pd[(size_t)2*row+1] * 2.f - 1.f;
  float ix = ((gx + 1.f) * 56.f - 1.f) * 0.5f;
  float iy = ((gy + 1.f) * 56.f - 1.f) * 0.5f;
  float x0 = floorf(ix), y0 = floorf(iy);
  float wx1 = ix - x0, wy1 = iy - y0;
  float wx0 = 1.f - wx1, wy0 = 1.f - wy1;
  float4 acc = make_float4(0.f, 0.f, 0.f, 0.f);
#pragma unroll
  for (int cy = 0; cy < 2; ++cy) {
#pragma unroll
    for (int cx = 0; cx < 2; ++cx) {
      float xc = x0 + (float)cx, yc = y0 + (float)cy;
      float wgt = (cx ? wx1 : wx0) * (cy ? wy1 : wy0);
      bool valid = (xc >= 0.f) && (xc < 56.f) && (yc >= 0.f) && (yc < 56.f);
      if (valid) {
        int lin = (int)yc * 56 + (int)xc;
        float4 pv = ((const float4*)(pe + (size_t)lin * 128))[lane];
        acc.x += wgt * pv.x; acc.y += wgt * pv.y;
        acc.z += wgt * pv.z; acc.w += wgt * pv.w;
      }
    }
  }
  float4* op = (float4*)(out + (size_t)row * 128) + lane;
  float4 cur = *op;
  cur.x += acc.x; cur.y += acc.y; cur.z += acc.z; cur.w += acc.w;
  *op = cur;
}

// ---------------------------------------------------------------------------
// launcher
// ---------------------------------------------------------------------------
extern "C" void kernel_launch(void* const* d_in, const int* in_sizes, int n_in,
                              void* d_out, int out_size, void* d_ws, size_t ws_size,
                              hipStream_t stream) {
  const float* x      = (const float*)d_in[0];
  const float* pos    = (const float*)d_in[1];
  const float* pe     = (const float*)d_in[2];
  const float* nu     = (const float*)d_in[3];
  const float* norm_g = (const float*)d_in[4];
  const float* norm_b = (const float*)d_in[5];
  const float* conf_w = (const float*)d_in[6];
  const float* conf_b = (const float*)d_in[7];
  const float* n1g    = (const float*)d_in[8];
  const float* n1b    = (const float*)d_in[9];
  const float* q_w    = (const float*)d_in[10];
  const float* k_w    = (const float*)d_in[11];
  const float* v_w    = (const float*)d_in[12];
  const float* proj_w = (const float*)d_in[13];
  const float* proj_b = (const float*)d_in[14];
  const float* sr_w   = (const float*)d_in[15];
  const float* sr_b   = (const float*)d_in[16];
  const float* srn_g  = (const float*)d_in[17];
  const float* srn_b  = (const float*)d_in[18];
  const float* fc_w   = (const float*)d_in[19];
  const float* fc_b   = (const float*)d_in[20];
  const float* n2g    = (const float*)d_in[21];
  const float* n2b    = (const float*)d_in[22];
  const float* fc1_w  = (const float*)d_in[23];
  const float* fc1_b  = (const float*)d_in[24];
  const float* fc2_w  = (const float*)d_in[25];
  const float* fc2_b  = (const float*)d_in[26];

  char* ws = (char*)d_ws;
  // workspace layout (bytes); total 190,578,688
  double*         scores = (double*)(ws + 0);                //  1,580,544
  int*            idx    = (int*)(ws + 1605632);             //    200,704
  float*          xd     = (float*)(ws + 1835008);           // 13,647,872
  float*          xn     = (float*)(ws + 15728640);          // 13,647,872
  float*          pd     = (float*)(ws + 29491200);          //    426,496
  float*          qb     = (float*)(ws + 30408704);          // 27,295,744; P alias; later O2
  float*          ob     = (float*)(ws + 58720256);          // 27,295,744; P tail alias; later xn2
  float*          wt     = (float*)(ws + 86507520);          //    262,144
  char*           big    = ws + 87031808;                    // 103,546,880 region
  float*          S      = (float*)big;                      // 52,183,040 (exclusive; dead after filter)
  float*          P      = (float*)(ws + 30408704);          // 51,380,224 (alias qb..ob; dead after conv)
  float*          xs_c   = (float*)big;                      //  3,211,264 (reuses S after filter)
  float*          xs_n   = (float*)(big + 3211264);          //  3,211,264
  float*          kbuf   = (float*)(big + 6422528);          //  6,422,528
  float*          vbuf   = (float*)(big + 12845056);         //  6,422,528
  float*          O2     = qb;
  float*          xn2    = ob;
  float*          out    = (float*)d_out;

  // 1) f64 conf+gumbel scores
  k_conf<<<(B_ * N_) / 256, 256, 0, stream>>>(x, norm_g, norm_b, conf_w, conf_b, nu, scores);
  // 2) top-784 per batch (f64 keys)
  k_topk<<<B_, 256, 0, stream>>>(scores, idx);
  // 3) gather + LN(norm1)
  k_gather_ln<<<(B_ * ND + 255) / 256, 256, 0, stream>>>(x, pos, idx, n1g, n1b, xd, xn, pd);
  // 4) token2map scatter (wave-per-token, coalesced atomics, f64 binning)
  hipMemsetAsync(S, 0, (size_t)B_ * HW * 65 * sizeof(float), stream);
  k_scatter<<<(B_ * N_ * 64) / 256, 256, 0, stream>>>(x, n1g, n1b, pos, S);
  // 5) normalize + gaussian reconstruct -> patch layout (f32)
  k_filter<<<(B_ * HW) / 256, 256, 0, stream>>>(S, P);
  // 6) conv weights transpose, conv-as-GEMM, srnorm
  k_wt<<<(1024 * 64) / 256, 256, 0, stream>>>(sr_w, wt);
  dim3 g_conv(NS * B_ / 64, 1);
  k_gemm<<<g_conv, 256, 0, stream>>>(P, wt, sr_b, nullptr, xs_c, B_ * NS, 64, 1024);
  k_ln64<<<(B_ * NS + 255) / 256, 256, 0, stream>>>(xs_c, srn_g, srn_b, xs_n, B_ * NS);
  // 7) k, v, q projections (q GEMM overwrites P region -- P is dead by now)
  dim3 g_kv(B_ * NS / 64, 2);
  k_gemm<<<g_kv, 256, 0, stream>>>(xs_n, k_w, nullptr, nullptr, kbuf, B_ * NS, 128, 64);
  k_gemm<<<g_kv, 256, 0, stream>>>(xs_n, v_w, nullptr, nullptr, vbuf, B_ * NS, 128, 64);
  dim3 g_row(B_ * ND / 64, 2);
  k_gemm<<<g_row, 256, 0, stream>>>(xn, q_w, nullptr, nullptr, qb, B_ * ND, 128, 64);
  // 8) attention (two-phase f32)
  k_attn<<<B_ * 2 * 14, 256, 0, stream>>>(qb, kbuf, vbuf, ob);
  // 9) x2 = x_down@fc_w + fc_b + (o@proj_w + proj_b)  -> d_out
  k_gemm<<<g_row, 256, 0, stream>>>(ob, proj_w, proj_b, nullptr, O2, B_ * ND, 128, 128);
  k_gemm<<<g_row, 256, 0, stream>>>(xd, fc_w, fc_b, O2, out, B_ * ND, 128, 64);
  // 10) fused MLP: out += gelu(LN(out)@fc1)@fc2
  k_ln128<<<(B_ * ND + 255) / 256, 256, 0, stream>>>(out, n2g, n2b, xn2, B_ * ND);
  k_mlp<<<B_ * ND / 64, 256, 0, stream>>>(xn2, fc1_w, fc1_b, fc2_w, fc2_b, out);
  // 11) + pos_feat (bilinear grid sample)
  k_posfeat<<<(B_ * ND * 32) / 256, 256, 0, stream>>>(pd, pe, out);
}

// Round 6
// 1127.073 us; speedup vs baseline: 1.9970x; 1.4789x over previous
//
#include <hip/hip_runtime.h>
#include <math.h>

#define DEVINL __device__ __forceinline__

constexpr int B_ = 64;
constexpr int N_ = 3136;
constexpr int C_ = 64;        // DIM
constexpr int NG = 49;        // N_grid
constexpr int NSAMP = 784;    // SAMPLE_NUM
constexpr int ND = NG + NSAMP;     // 833
constexpr int NREST = N_ - NG;     // 3087
constexpr int H_ = 56, W_ = 56;
constexpr int HW = H_ * W_;        // 3136
constexpr int NS = 14 * 14;        // 196 kv tokens
constexpr int KPAD = 224;          // 196 padded to 7*32
constexpr float LN_EPS = 1e-5f;
constexpr float EPS6 = 1e-6f;

typedef __attribute__((ext_vector_type(8))) short short8;
typedef __attribute__((ext_vector_type(4))) float f32x4;

DEVINL unsigned short f2bf(float f) {
  unsigned int u = __float_as_uint(f);
  unsigned int r = u + 0x7FFFu + ((u >> 16) & 1u);
  return (unsigned short)(r >> 16);
}

// ---------------------------------------------------------------------------
// K1: conf scores in FP64 (discrete top-k decision must match f64 np ref)
// ---------------------------------------------------------------------------
__global__ __launch_bounds__(256) void k_conf(
    const float* __restrict__ x, const float* __restrict__ ng, const float* __restrict__ nb,
    const float* __restrict__ cw, const float* __restrict__ cb,
    const float* __restrict__ nu, double* __restrict__ scores) {
  int t = blockIdx.x * 256 + threadIdx.x;
  if (t >= B_ * N_) return;
  int b = t / N_, n = t - b * N_;
  if (n < NG) return;
  const float4* row = (const float4*)(x + (size_t)t * C_);
  float v[C_];
#pragma unroll
  for (int i = 0; i < 16; ++i) {
    float4 r = row[i];
    v[4*i] = r.x; v[4*i+1] = r.y; v[4*i+2] = r.z; v[4*i+3] = r.w;
  }
  double sd = 0.0;
#pragma unroll
  for (int i = 0; i < C_; ++i) sd += (double)v[i];
  double md = sd * (1.0/64.0);
  double vd = 0.0;
#pragma unroll
  for (int i = 0; i < C_; ++i) { double d = (double)v[i] - md; vd += d * d; }
  vd *= (1.0/64.0);
  double rsd = 1.0 / sqrt(vd + 1e-5);
  double conf = (double)cb[0];
#pragma unroll
  for (int i = 0; i < C_; ++i) {
    double xnv = ((double)v[i] - md) * rsd;
    conf += (xnv * (double)ng[i] + (double)nb[i]) * (double)cw[i];
  }
  double u = (double)nu[(size_t)b * NREST + (n - NG)];
  double noise = -log(-log(u + 1e-6) + 1e-6);
  scores[(size_t)b * NREST + (n - NG)] = conf + noise;
}

// ---------------------------------------------------------------------------
// K2: per-batch top-784 of 3087 via bitonic sort of (f64-key, idx) in LDS.
// ---------------------------------------------------------------------------
__global__ __launch_bounds__(256) void k_topk(const double* __restrict__ scores, int* __restrict__ idx) {
  __shared__ unsigned long long ks[4096];
  __shared__ unsigned int is_[4096];
  int b = blockIdx.x;
  int tid = threadIdx.x;
  const double* sc = scores + (size_t)b * NREST;
  for (int i = tid; i < 4096; i += 256) {
    if (i < NREST) {
      long long bits = __double_as_longlong(sc[i]);
      unsigned long long ub = (unsigned long long)bits;
      ub = (bits < 0) ? ~ub : (ub | 0x8000000000000000ULL);  // monotone map
      ks[i] = ~ub;               // ascending key == descending score
      is_[i] = (unsigned int)i;
    } else {
      ks[i] = 0xFFFFFFFFFFFFFFFFULL;
      is_[i] = 0xFFFFFFFFu;
    }
  }
  __syncthreads();
  for (int k = 2; k <= 4096; k <<= 1) {
    for (int j = k >> 1; j > 0; j >>= 1) {
      for (int i = tid; i < 4096; i += 256) {
        int l = i ^ j;
        if (l > i) {
          unsigned long long ka = ks[i], kc = ks[l];
          unsigned int ia = is_[i], ic = is_[l];
          bool agtc = (ka > kc) || (ka == kc && ia > ic);
          bool up = ((i & k) == 0);
          if (up == agtc) { ks[i] = kc; ks[l] = ka; is_[i] = ic; is_[l] = ia; }
        }
      }
      __syncthreads();
    }
  }
  for (int r = tid; r < NSAMP; r += 256)
    idx[(size_t)b * NSAMP + r] = (int)is_[r];
}

// ---------------------------------------------------------------------------
// K3: gather x_down/pos_down rows; LayerNorm(x_down, norm1) -> xn
// ---------------------------------------------------------------------------
__global__ __launch_bounds__(256) void k_gather_ln(
    const float* __restrict__ x, const float* __restrict__ pos, const int* __restrict__ idx,
    const float* __restrict__ n1g, const float* __restrict__ n1b,
    float* __restrict__ xd, float* __restrict__ xn, float* __restrict__ pd) {
  int t = blockIdx.x * 256 + threadIdx.x;
  if (t >= B_ * ND) return;
  int b = t / ND, r = t - b * ND;
  int srcn = (r < NG) ? r : (NG + idx[(size_t)b * NSAMP + (r - NG)]);
  const float4* row = (const float4*)(x + ((size_t)b * N_ + srcn) * C_);
  float4* xdr = (float4*)(xd + (size_t)t * C_);
  float v[C_];
  float s = 0.f, ss = 0.f;
#pragma unroll
  for (int i = 0; i < 16; ++i) {
    float4 rr = row[i];
    xdr[i] = rr;
    v[4*i] = rr.x; v[4*i+1] = rr.y; v[4*i+2] = rr.z; v[4*i+3] = rr.w;
    s += rr.x + rr.y + rr.z + rr.w;
    ss += rr.x*rr.x + rr.y*rr.y + rr.z*rr.z + rr.w*rr.w;
  }
  float m = s * (1.f/64.f);
  float var = ss * (1.f/64.f) - m*m;
  float rs = rsqrtf(var + LN_EPS);
#pragma unroll
  for (int i = 0; i < C_; ++i)
    xn[(size_t)t * C_ + i] = (v[i] - m) * rs * n1g[i] + n1b[i];
  pd[(size_t)2*t]   = pos[((size_t)b * N_ + srcn) * 2];
  pd[(size_t)2*t+1] = pos[((size_t)b * N_ + srcn) * 2 + 1];
}

// ---------------------------------------------------------------------------
// K4: scatter: one WAVE per token, lane = channel; coalesced atomics.
// ---------------------------------------------------------------------------
__global__ __launch_bounds__(256) void k_scatter(
    const float* __restrict__ x, const float* __restrict__ n1g, const float* __restrict__ n1b,
    const float* __restrict__ pos, float* __restrict__ S) {
  int gt = blockIdx.x * 256 + threadIdx.x;
  int tok = gt >> 6, lane = gt & 63;
  if (tok >= B_ * N_) return;
  int b = tok / N_;
  float v = x[(size_t)tok * C_ + lane];
  float s = v, ss = v * v;
#pragma unroll
  for (int m = 32; m > 0; m >>= 1) {
    s += __shfl_xor(s, m);
    ss += __shfl_xor(ss, m);
  }
  float mean = s * (1.f/64.f);
  float var = ss * (1.f/64.f) - mean * mean;
  float rs = rsqrtf(var + LN_EPS);
  double px = fmin(fmax((double)pos[(size_t)2*tok],   0.0), 1.0) * (double)(W_ - 1);
  double py = fmin(fmax((double)pos[(size_t)2*tok+1], 0.0), 1.0) * (double)(H_ - 1);
  int xi = (int)rint(px), yi = (int)rint(py);
  float* base = S + ((size_t)b * HW + yi * W_ + xi) * 65;
  atomicAdd(base + lane, (v - mean) * rs * n1g[lane] + n1b[lane]);
  if (lane == 0) atomicAdd(base + 64, 1.f);
}

// ---------------------------------------------------------------------------
// K5: normalize + masked 3x3 gaussian reconstruct -> conv-patch layout (f32)
// ---------------------------------------------------------------------------
__global__ __launch_bounds__(256) void k_filter(const float* __restrict__ S, float* __restrict__ P) {
  int t = blockIdx.x * 256 + threadIdx.x;
  if (t >= B_ * HW) return;
  int b = t / HW, p = t - b * HW;
  int y = p / W_, x = p - y * W_;
  const float* Sb = S + (size_t)b * HW * 65;
  const float e1 = 0.882496902584595f;   // exp(-1/8)
  const float e2 = 0.778800783071405f;   // exp(-1/4)
  const float Z = 1.f + 4.f * (e1 + e2);
  float m0 = Sb[(size_t)p * 65 + 64];
  float mb0 = m0 > 0.f ? 1.f : 0.f;
  float cfac = mb0 / (m0 + EPS6);
  float scale[9];
  int off[9];
  float mi = 0.f;
  int kk = 0;
#pragma unroll
  for (int dy = -1; dy <= 1; ++dy) {
#pragma unroll
    for (int dx = -1; dx <= 1; ++dx) {
      int ny = y + dy, nx = x + dx;
      float w = ((dx == 0 && dy == 0) ? 1.f : ((dx*dx + dy*dy) == 1 ? e1 : e2)) / Z;
      bool in = (ny >= 0 && ny < H_ && nx >= 0 && nx < W_);
      int np = in ? (ny * W_ + nx) : p;
      float mm = in ? Sb[(size_t)np * 65 + 64] : 0.f;
      float mb = mm > 0.f ? 1.f : 0.f;
      mi += w * mb;
      scale[kk] = in ? (w * mb / (mm + EPS6)) : 0.f;
      off[kk] = np * 65;
      ++kk;
    }
  }
  float inv_mi = (mi > 0.f ? 1.f : 0.f) / (mi + EPS6);
  float outer = (1.f - mb0) * inv_mi;
  int j = (y >> 2) * 14 + (x >> 2);
  int colb = (y & 3) * 4 + (x & 3);
  float* Pr = P + ((size_t)b * NS + j) * 1024 + colb;
  size_t pc = (size_t)p * 65;
  for (int c = 0; c < C_; ++c) {
    float fs = 0.f;
#pragma unroll
    for (int q = 0; q < 9; ++q) fs += scale[q] * Sb[(size_t)off[q] + c];
    Pr[c * 16] = Sb[pc + c] * cfac + outer * fs;
  }
}

// ---------------------------------------------------------------------------
// K6: transpose sr_w (co,ci,ky,kx) -> w_t[kk=ci*16+ky*4+kx][co]
// ---------------------------------------------------------------------------
__global__ __launch_bounds__(256) void k_wt(const float* __restrict__ srw, float* __restrict__ wt) {
  int t = blockIdx.x * 256 + threadIdx.x;
  if (t >= 1024 * 64) return;
  int kk = t >> 6, co = t & 63;
  int ci = kk >> 4, r = kk & 15;
  wt[t] = srw[(((size_t)co * 64 + ci) << 4) + r];
}

// ---------------------------------------------------------------------------
// Tiled fp32 GEMM: C[M,N] = A[M,K] @ B[K,N] (+bias)(+add)
// ---------------------------------------------------------------------------
__global__ __launch_bounds__(256) void k_gemm(
    const float* __restrict__ A, const float* __restrict__ Bw,
    const float* __restrict__ bias, const float* __restrict__ add,
    float* __restrict__ Cout, int M, int N, int K) {
  __shared__ float sA[16][68];
  __shared__ float sB[16][64];
  int bm = blockIdx.x * 64, bn = blockIdx.y * 64;
  int tid = threadIdx.x;
  int tx = tid & 15, ty = tid >> 4;
  float acc[4][4] = {{0.f}};
  for (int k0 = 0; k0 < K; k0 += 16) {
    int e = tid << 2;
    int am = e >> 4, ak = e & 15;
    float4 a4 = *(const float4*)(A + (size_t)(bm + am) * K + k0 + ak);
    sA[ak + 0][am] = a4.x; sA[ak + 1][am] = a4.y; sA[ak + 2][am] = a4.z; sA[ak + 3][am] = a4.w;
    int bk = e >> 6, nn = e & 63;
    float4 b4 = *(const float4*)(Bw + (size_t)(k0 + bk) * N + bn + nn);
    *(float4*)&sB[bk][nn] = b4;
    __syncthreads();
#pragma unroll
    for (int kk = 0; kk < 16; ++kk) {
      float a[4], bb[4];
#pragma unroll
      for (int i = 0; i < 4; ++i) a[i] = sA[kk][ty * 4 + i];
#pragma unroll
      for (int i = 0; i < 4; ++i) bb[i] = sB[kk][tx * 4 + i];
#pragma unroll
      for (int i = 0; i < 4; ++i)
#pragma unroll
        for (int jj = 0; jj < 4; ++jj) acc[i][jj] += a[i] * bb[jj];
    }
    __syncthreads();
  }
#pragma unroll
  for (int i = 0; i < 4; ++i) {
    int row = bm + ty * 4 + i;
#pragma unroll
    for (int jj = 0; jj < 4; ++jj) {
      int col = bn + tx * 4 + jj;
      float v = acc[i][jj];
      if (bias) v += bias[col];
      if (add) v += add[(size_t)row * N + col];
      Cout[(size_t)row * N + col] = v;
    }
  }
}

// ---------------------------------------------------------------------------
// Fused MLP: out += gelu(xn2 @ W1 + b1) @ W2 + b2
// ---------------------------------------------------------------------------
__global__ __launch_bounds__(256) void k_mlp(
    const float* __restrict__ A, const float* __restrict__ W1, const float* __restrict__ b1,
    const float* __restrict__ W2, const float* __restrict__ b2, float* __restrict__ out) {
  __shared__ float sA[16][68];
  __shared__ float sW1[16][64];
  __shared__ float sH[64][66];
  __shared__ float sW2[16][128];
  int bm = blockIdx.x * 64;
  int tid = threadIdx.x;
  int tx = tid & 15, ty = tid >> 4;
  float acc2[4][8];
#pragma unroll
  for (int i = 0; i < 4; ++i)
#pragma unroll
    for (int j = 0; j < 8; ++j) acc2[i][j] = 0.f;

  for (int hc = 0; hc < 8; ++hc) {
    float acc1[4][4];
#pragma unroll
    for (int i = 0; i < 4; ++i)
#pragma unroll
      for (int j = 0; j < 4; ++j) acc1[i][j] = 0.f;
    for (int k0 = 0; k0 < 128; k0 += 16) {
      int e = tid << 2;
      int am = e >> 4, ak = e & 15;
      float4 a4 = *(const float4*)(A + (size_t)(bm + am) * 128 + k0 + ak);
      sA[ak + 0][am] = a4.x; sA[ak + 1][am] = a4.y; sA[ak + 2][am] = a4.z; sA[ak + 3][am] = a4.w;
      int bk = e >> 6, nn = e & 63;
      float4 w4 = *(const float4*)(W1 + (size_t)(k0 + bk) * 512 + hc * 64 + nn);
      *(float4*)&sW1[bk][nn] = w4;
      __syncthreads();
#pragma unroll
      for (int kk = 0; kk < 16; ++kk) {
        float a[4], bb[4];
#pragma unroll
        for (int i = 0; i < 4; ++i) a[i] = sA[kk][ty * 4 + i];
#pragma unroll
        for (int i = 0; i < 4; ++i) bb[i] = sW1[kk][tx * 4 + i];
#pragma unroll
        for (int i = 0; i < 4; ++i)
#pragma unroll
          for (int jj = 0; jj < 4; ++jj) acc1[i][jj] += a[i] * bb[jj];
      }
      __syncthreads();
    }
#pragma unroll
    for (int i = 0; i < 4; ++i)
#pragma unroll
      for (int j = 0; j < 4; ++j) {
        float v = acc1[i][j] + b1[hc * 64 + tx * 4 + j];
        sH[ty * 4 + i][tx * 4 + j] = 0.5f * v * (1.f + erff(v * 0.70710678118654752f));
      }
    __syncthreads();
    for (int k0b = 0; k0b < 64; k0b += 16) {
      int e = tid << 3;
      int rw = e >> 7, cl = e & 127;
      float4 w4a = *(const float4*)(W2 + (size_t)(hc * 64 + k0b + rw) * 128 + cl);
      float4 w4b = *(const float4*)(W2 + (size_t)(hc * 64 + k0b + rw) * 128 + cl + 4);
      *(float4*)&sW2[rw][cl] = w4a;
      *(float4*)&sW2[rw][cl + 4] = w4b;
      __syncthreads();
#pragma unroll
      for (int kk = 0; kk < 16; ++kk) {
        float hvals[4], wv[8];
#pragma unroll
        for (int i = 0; i < 4; ++i) hvals[i] = sH[ty * 4 + i][k0b + kk];
#pragma unroll
        for (int j = 0; j < 8; ++j) wv[j] = sW2[kk][tx * 8 + j];
#pragma unroll
        for (int i = 0; i < 4; ++i)
#pragma unroll
          for (int j = 0; j < 8; ++j) acc2[i][j] += hvals[i] * wv[j];
      }
      __syncthreads();
    }
  }
#pragma unroll
  for (int i = 0; i < 4; ++i) {
    int row = bm + ty * 4 + i;
#pragma unroll
    for (int j = 0; j < 8; ++j) {
      int col = tx * 8 + j;
      out[(size_t)row * 128 + col] += acc2[i][j] + b2[col];
    }
  }
}

// ---------------------------------------------------------------------------
// LayerNorm kernels (dim 128 / dim 64), one thread per row
// ---------------------------------------------------------------------------
__global__ __launch_bounds__(256) void k_ln128(const float* __restrict__ in, const float* __restrict__ g,
    const float* __restrict__ bb, float* __restrict__ out, int rows) {
  int t = blockIdx.x * 256 + threadIdx.x;
  if (t >= rows) return;
  const float4* row = (const float4*)(in + (size_t)t * 128);
  float4 v[32];
  float s = 0.f, ss = 0.f;
#pragma unroll
  for (int i = 0; i < 32; ++i) {
    float4 r = row[i]; v[i] = r;
    s += r.x + r.y + r.z + r.w;
    ss += r.x*r.x + r.y*r.y + r.z*r.z + r.w*r.w;
  }
  float m = s * (1.f/128.f);
  float var = ss * (1.f/128.f) - m*m;
  float rs = rsqrtf(var + LN_EPS);
  float4* orow = (float4*)(out + (size_t)t * 128);
#pragma unroll
  for (int i = 0; i < 32; ++i) {
    float4 r = v[i];
    float4 o;
    o.x = (r.x - m) * rs * g[4*i+0] + bb[4*i+0];
    o.y = (r.y - m) * rs * g[4*i+1] + bb[4*i+1];
    o.z = (r.z - m) * rs * g[4*i+2] + bb[4*i+2];
    o.w = (r.w - m) * rs * g[4*i+3] + bb[4*i+3];
    orow[i] = o;
  }
}

__global__ __launch_bounds__(256) void k_ln64(const float* __restrict__ in, const float* __restrict__ g,
    const float* __restrict__ bb, float* __restrict__ out, int rows) {
  int t = blockIdx.x * 256 + threadIdx.x;
  if (t >= rows) return;
  const float4* row = (const float4*)(in + (size_t)t * 64);
  float v[64];
  float s = 0.f, ss = 0.f;
#pragma unroll
  for (int i = 0; i < 16; ++i) {
    float4 r = row[i];
    v[4*i] = r.x; v[4*i+1] = r.y; v[4*i+2] = r.z; v[4*i+3] = r.w;
    s += r.x + r.y + r.z + r.w;
    ss += r.x*r.x + r.y*r.y + r.z*r.z + r.w*r.w;
  }
  float m = s * (1.f/64.f);
  float var = ss * (1.f/64.f) - m*m;
  float rs = rsqrtf(var + LN_EPS);
#pragma unroll
  for (int i = 0; i < 64; ++i)
    out[(size_t)t * 64 + i] = (v[i] - m) * rs * g[i] + bb[i];
}

// ---------------------------------------------------------------------------
// K7 (ROUND-5 REWRITE): MFMA attention, mfma_f32_16x16x32_bf16.
// grid = B * 2 heads * 14 query-chunks of 64; 4 waves, wave = 16-query strip.
// A layout: [m=lane&15][k=quad*8+j]; C/D: col=lane&15, row=quad*4+reg (m89).
// K staged bf16 w/ XOR-swizzled 16B chunks (b128 B-frags, 2-way = free);
// V natural stride-72 bf16 (scalar u16 B-frags, <=2-way);
// P (normalized, bf16) overwrites K region after a barrier.
// LDS = 29,696 + 32,256 = 61,952 B -> 2 blocks/CU.
// ---------------------------------------------------------------------------
__global__ __launch_bounds__(256) void k_attn(const float* __restrict__ q,
    const float* __restrict__ kg, const float* __restrict__ vg, float* __restrict__ o) {
  __shared__ __align__(16) unsigned short ldsKP[14848]; // K swizzled (28672B) / P 64x232 (29696B)
  __shared__ __align__(16) unsigned short ldsV[16128];  // V[224][72]
  int blk = blockIdx.x;
  int chunk = blk % 14;
  int bh = blk / 14;
  int h = bh & 1, b = bh >> 1;
  int tid = threadIdx.x;
  int wv = tid >> 6, lane = tid & 63;
  int quad = lane >> 4, l16 = lane & 15;

  const float* kb = kg + (size_t)b * NS * 128 + h * 64;
  const float* vb = vg + (size_t)b * NS * 128 + h * 64;

  // ---- stage K (swizzled) and V (natural), zero-pad keys >= 196 ----
  for (int t = tid; t < KPAD * 8; t += 256) {
    int key = t >> 3, ck = t & 7;
    short8 pk, pv;
    if (key < NS) {
      const float* ksrc = kb + (size_t)key * 128 + ck * 8;
      const float* vsrc = vb + (size_t)key * 128 + ck * 8;
      float4 a = *(const float4*)ksrc;
      float4 c = *(const float4*)(ksrc + 4);
      pk[0]=(short)f2bf(a.x); pk[1]=(short)f2bf(a.y); pk[2]=(short)f2bf(a.z); pk[3]=(short)f2bf(a.w);
      pk[4]=(short)f2bf(c.x); pk[5]=(short)f2bf(c.y); pk[6]=(short)f2bf(c.z); pk[7]=(short)f2bf(c.w);
      float4 e = *(const float4*)vsrc;
      float4 g = *(const float4*)(vsrc + 4);
      pv[0]=(short)f2bf(e.x); pv[1]=(short)f2bf(e.y); pv[2]=(short)f2bf(e.z); pv[3]=(short)f2bf(e.w);
      pv[4]=(short)f2bf(g.x); pv[5]=(short)f2bf(g.y); pv[6]=(short)f2bf(g.z); pv[7]=(short)f2bf(g.w);
    } else {
      pk = (short8)0; pv = (short8)0;
    }
    *(short8*)&ldsKP[key * 64 + ((ck ^ (key & 7)) << 3)] = pk;
    *(short8*)&ldsV[key * 72 + ck * 8] = pv;
  }

  // ---- Q A-frags straight from global (row-clamped for the tail chunk) ----
  int qrow = chunk * 64 + wv * 16 + l16;
  int qrowc = qrow < ND ? qrow : ND - 1;
  const float* qsrc = q + ((size_t)b * ND + qrowc) * 128 + h * 64 + quad * 8;
  short8 aq0, aq1;
  {
    float4 a = *(const float4*)qsrc;
    float4 c = *(const float4*)(qsrc + 4);
    aq0[0]=(short)f2bf(a.x); aq0[1]=(short)f2bf(a.y); aq0[2]=(short)f2bf(a.z); aq0[3]=(short)f2bf(a.w);
    aq0[4]=(short)f2bf(c.x); aq0[5]=(short)f2bf(c.y); aq0[6]=(short)f2bf(c.z); aq0[7]=(short)f2bf(c.w);
    float4 e = *(const float4*)(qsrc + 32);
    float4 g = *(const float4*)(qsrc + 36);
    aq1[0]=(short)f2bf(e.x); aq1[1]=(short)f2bf(e.y); aq1[2]=(short)f2bf(e.z); aq1[3]=(short)f2bf(e.w);
    aq1[4]=(short)f2bf(g.x); aq1[5]=(short)f2bf(g.y); aq1[6]=(short)f2bf(g.z); aq1[7]=(short)f2bf(g.w);
  }
  __syncthreads();

  // ---- S = Q @ K^T : 14 col-tiles of 16 keys ----
  f32x4 acc[14];
#pragma unroll
  for (int ct = 0; ct < 14; ++ct) {
    int key = ct * 16 + l16;
    short8 bk0 = *(const short8*)&ldsKP[key * 64 + ((quad ^ (key & 7)) << 3)];
    short8 bk1 = *(const short8*)&ldsKP[key * 64 + (((4 + quad) ^ (key & 7)) << 3)];
    f32x4 z = {0.f, 0.f, 0.f, 0.f};
    z = __builtin_amdgcn_mfma_f32_16x16x32_bf16(aq0, bk0, z, 0, 0, 0);
    z = __builtin_amdgcn_mfma_f32_16x16x32_bf16(aq1, bk1, z, 0, 0, 0);
    acc[ct] = z;
  }

  // ---- softmax over 224 cols (pad cols -> -1e30 -> exp 0) ----
  const float scale = 0.17677669529663687f;  // 32^-0.5
  float rmax[4] = {-1e30f, -1e30f, -1e30f, -1e30f};
#pragma unroll
  for (int ct = 0; ct < 14; ++ct) {
    bool msk = (ct * 16 + l16) >= NS;
#pragma unroll
    for (int r = 0; r < 4; ++r) {
      float sv = msk ? -1e30f : acc[ct][r] * scale;
      acc[ct][r] = sv;
      rmax[r] = fmaxf(rmax[r], sv);
    }
  }
#pragma unroll
  for (int m = 1; m < 16; m <<= 1)
#pragma unroll
    for (int r = 0; r < 4; ++r) rmax[r] = fmaxf(rmax[r], __shfl_xor(rmax[r], m));
  float rsum[4] = {0.f, 0.f, 0.f, 0.f};
#pragma unroll
  for (int ct = 0; ct < 14; ++ct)
#pragma unroll
    for (int r = 0; r < 4; ++r) {
      float e = __expf(acc[ct][r] - rmax[r]);
      acc[ct][r] = e;
      rsum[r] += e;
    }
#pragma unroll
  for (int m = 1; m < 16; m <<= 1)
#pragma unroll
    for (int r = 0; r < 4; ++r) rsum[r] += __shfl_xor(rsum[r], m);
  float rinv[4];
#pragma unroll
  for (int r = 0; r < 4; ++r) rinv[r] = 1.f / rsum[r];

  __syncthreads();   // everyone done reading K region

  // ---- write normalized P (bf16) into K region: P[64][232] ----
#pragma unroll
  for (int ct = 0; ct < 14; ++ct)
#pragma unroll
    for (int r = 0; r < 4; ++r) {
      int prow = wv * 16 + quad * 4 + r;
      ldsKP[prow * 232 + ct * 16 + l16] = f2bf(acc[ct][r] * rinv[r]);
    }
  __syncthreads();

  // ---- O = P @ V : 4 out col-tiles, 7 k-chunks of 32 keys ----
  f32x4 oacc[4];
#pragma unroll
  for (int ot = 0; ot < 4; ++ot) oacc[ot] = (f32x4){0.f, 0.f, 0.f, 0.f};
#pragma unroll
  for (int kc = 0; kc < 7; ++kc) {
    short8 ap = *(const short8*)&ldsKP[(wv * 16 + l16) * 232 + kc * 32 + quad * 8];
    int keybase = kc * 32 + quad * 8;
#pragma unroll
    for (int ot = 0; ot < 4; ++ot) {
      int dcol = ot * 16 + l16;
      short8 bv;
#pragma unroll
      for (int j = 0; j < 8; ++j) bv[j] = (short)ldsV[(keybase + j) * 72 + dcol];
      oacc[ot] = __builtin_amdgcn_mfma_f32_16x16x32_bf16(ap, bv, oacc[ot], 0, 0, 0);
    }
  }

  // ---- write O (C-layout: col=l16, row=quad*4+reg) ----
#pragma unroll
  for (int ot = 0; ot < 4; ++ot)
#pragma unroll
    for (int r = 0; r < 4; ++r) {
      int rowg = chunk * 64 + wv * 16 + quad * 4 + r;
      if (rowg < ND)
        o[((size_t)b * ND + rowg) * 128 + h * 64 + ot * 16 + l16] = oacc[ot][r];
    }
}

// ---------------------------------------------------------------------------
// K8: bilinear grid-sample of pos_embed at pos_down, accumulate into out
// ---------------------------------------------------------------------------
__global__ __launch_bounds__(256) void k_posfeat(const float* __restrict__ pd,
    const float* __restrict__ pe, float* __restrict__ out) {
  int t = blockIdx.x * 256 + threadIdx.x;
  int row = t >> 5, lane = t & 31;
  if (row >= B_ * ND) return;
  float gx = pd[(size_t)2*row] * 2.f - 1.f;
  float gy = pd[(size_t)2*row+1] * 2.f - 1.f;
  float ix = ((gx + 1.f) * 56.f - 1.f) * 0.5f;
  float iy = ((gy + 1.f) * 56.f - 1.f) * 0.5f;
  float x0 = floorf(ix), y0 = floorf(iy);
  float wx1 = ix - x0, wy1 = iy - y0;
  float wx0 = 1.f - wx1, wy0 = 1.f - wy1;
  float4 acc = make_float4(0.f, 0.f, 0.f, 0.f);
#pragma unroll
  for (int cy = 0; cy < 2; ++cy) {
#pragma unroll
    for (int cx = 0; cx < 2; ++cx) {
      float xc = x0 + (float)cx, yc = y0 + (float)cy;
      float wgt = (cx ? wx1 : wx0) * (cy ? wy1 : wy0);
      bool valid = (xc >= 0.f) && (xc < 56.f) && (yc >= 0.f) && (yc < 56.f);
      if (valid) {
        int lin = (int)yc * 56 + (int)xc;
        float4 pv = ((const float4*)(pe + (size_t)lin * 128))[lane];
        acc.x += wgt * pv.x; acc.y += wgt * pv.y;
        acc.z += wgt * pv.z; acc.w += wgt * pv.w;
      }
    }
  }
  float4* op = (float4*)(out + (size_t)row * 128) + lane;
  float4 cur = *op;
  cur.x += acc.x; cur.y += acc.y; cur.z += acc.z; cur.w += acc.w;
  *op = cur;
}

// ---------------------------------------------------------------------------
// launcher
// ---------------------------------------------------------------------------
extern "C" void kernel_launch(void* const* d_in, const int* in_sizes, int n_in,
                              void* d_out, int out_size, void* d_ws, size_t ws_size,
                              hipStream_t stream) {
  const float* x      = (const float*)d_in[0];
  const float* pos    = (const float*)d_in[1];
  const float* pe     = (const float*)d_in[2];
  const float* nu     = (const float*)d_in[3];
  const float* norm_g = (const float*)d_in[4];
  const float* norm_b = (const float*)d_in[5];
  const float* conf_w = (const float*)d_in[6];
  const float* conf_b = (const float*)d_in[7];
  const float* n1g    = (const float*)d_in[8];
  const float* n1b    = (const float*)d_in[9];
  const float* q_w    = (const float*)d_in[10];
  const float* k_w    = (const float*)d_in[11];
  const float* v_w    = (const float*)d_in[12];
  const float* proj_w = (const float*)d_in[13];
  const float* proj_b = (const float*)d_in[14];
  const float* sr_w   = (const float*)d_in[15];
  const float* sr_b   = (const float*)d_in[16];
  const float* srn_g  = (const float*)d_in[17];
  const float* srn_b  = (const float*)d_in[18];
  const float* fc_w   = (const float*)d_in[19];
  const float* fc_b   = (const float*)d_in[20];
  const float* n2g    = (const float*)d_in[21];
  const float* n2b    = (const float*)d_in[22];
  const float* fc1_w  = (const float*)d_in[23];
  const float* fc1_b  = (const float*)d_in[24];
  const float* fc2_w  = (const float*)d_in[25];
  const float* fc2_b  = (const float*)d_in[26];

  char* ws = (char*)d_ws;
  // workspace layout (bytes); total 190,578,688
  double*         scores = (double*)(ws + 0);                //  1,580,544
  int*            idx    = (int*)(ws + 1605632);             //    200,704
  float*          xd     = (float*)(ws + 1835008);           // 13,647,872
  float*          xn     = (float*)(ws + 15728640);          // 13,647,872
  float*          pd     = (float*)(ws + 29491200);          //    426,496
  float*          qb     = (float*)(ws + 30408704);          // 27,295,744; P alias; later O2
  float*          ob     = (float*)(ws + 58720256);          // 27,295,744; P tail alias; later xn2
  float*          wt     = (float*)(ws + 86507520);          //    262,144
  char*           big    = ws + 87031808;                    // 103,546,880 region
  float*          S      = (float*)big;                      // 52,183,040 (exclusive; dead after filter)
  float*          P      = (float*)(ws + 30408704);          // 51,380,224 (alias qb..ob; dead after conv)
  float*          xs_c   = (float*)big;                      //  3,211,264 (reuses S after filter)
  float*          xs_n   = (float*)(big + 3211264);          //  3,211,264
  float*          kbuf   = (float*)(big + 6422528);          //  6,422,528
  float*          vbuf   = (float*)(big + 12845056);         //  6,422,528
  float*          O2     = qb;
  float*          xn2    = ob;
  float*          out    = (float*)d_out;

  // 1) f64 conf+gumbel scores
  k_conf<<<(B_ * N_) / 256, 256, 0, stream>>>(x, norm_g, norm_b, conf_w, conf_b, nu, scores);
  // 2) top-784 per batch (f64 keys)
  k_topk<<<B_, 256, 0, stream>>>(scores, idx);
  // 3) gather + LN(norm1)
  k_gather_ln<<<(B_ * ND + 255) / 256, 256, 0, stream>>>(x, pos, idx, n1g, n1b, xd, xn, pd);
  // 4) token2map scatter (wave-per-token, coalesced atomics, f64 binning)
  hipMemsetAsync(S, 0, (size_t)B_ * HW * 65 * sizeof(float), stream);
  k_scatter<<<(B_ * N_ * 64) / 256, 256, 0, stream>>>(x, n1g, n1b, pos, S);
  // 5) normalize + gaussian reconstruct -> patch layout (f32)
  k_filter<<<(B_ * HW) / 256, 256, 0, stream>>>(S, P);
  // 6) conv weights transpose, conv-as-GEMM, srnorm
  k_wt<<<(1024 * 64) / 256, 256, 0, stream>>>(sr_w, wt);
  dim3 g_conv(NS * B_ / 64, 1);
  k_gemm<<<g_conv, 256, 0, stream>>>(P, wt, sr_b, nullptr, xs_c, B_ * NS, 64, 1024);
  k_ln64<<<(B_ * NS + 255) / 256, 256, 0, stream>>>(xs_c, srn_g, srn_b, xs_n, B_ * NS);
  // 7) k, v, q projections (q GEMM overwrites P region -- P is dead by now)
  dim3 g_kv(B_ * NS / 64, 2);
  k_gemm<<<g_kv, 256, 0, stream>>>(xs_n, k_w, nullptr, nullptr, kbuf, B_ * NS, 128, 64);
  k_gemm<<<g_kv, 256, 0, stream>>>(xs_n, v_w, nullptr, nullptr, vbuf, B_ * NS, 128, 64);
  dim3 g_row(B_ * ND / 64, 2);
  k_gemm<<<g_row, 256, 0, stream>>>(xn, q_w, nullptr, nullptr, qb, B_ * ND, 128, 64);
  // 8) attention (MFMA bf16)
  k_attn<<<B_ * 2 * 14, 256, 0, stream>>>(qb, kbuf, vbuf, ob);
  // 9) x2 = x_down@fc_w + fc_b + (o@proj_w + proj_b)  -> d_out
  k_gemm<<<g_row, 256, 0, stream>>>(ob, proj_w, proj_b, nullptr, O2, B_ * ND, 128, 128);
  k_gemm<<<g_row, 256, 0, stream>>>(xd, fc_w, fc_b, O2, out, B_ * ND, 128, 64);
  // 10) fused MLP: out += gelu(LN(out)@fc1)@fc2
  k_ln128<<<(B_ * ND + 255) / 256, 256, 0, stream>>>(out, n2g, n2b, xn2, B_ * ND);
  k_mlp<<<B_ * ND / 64, 256, 0, stream>>>(xn2, fc1_w, fc1_b, fc2_w, fc2_b, out);
  // 11) + pos_feat (bilinear grid sample)
  k_posfeat<<<(B_ * ND * 32) / 256, 256, 0, stream>>>(pd, pe, out);
}

// Round 7
// 936.853 us; speedup vs baseline: 2.4025x; 1.2030x over previous
//
#include <hip/hip_runtime.h>
#include <math.h>

#define DEVINL __device__ __forceinline__

constexpr int B_ = 64;
constexpr int N_ = 3136;
constexpr int C_ = 64;        // DIM
constexpr int NG = 49;        // N_grid
constexpr int NSAMP = 784;    // SAMPLE_NUM
constexpr int ND = NG + NSAMP;     // 833
constexpr int NREST = N_ - NG;     // 3087
constexpr int H_ = 56, W_ = 56;
constexpr int HW = H_ * W_;        // 3136
constexpr int NS = 14 * 14;        // 196 kv tokens
constexpr int KPAD = 224;          // 196 padded to 7*32
constexpr float LN_EPS = 1e-5f;
constexpr float EPS6 = 1e-6f;

typedef __attribute__((ext_vector_type(8))) short short8;
typedef __attribute__((ext_vector_type(4))) float f32x4;

DEVINL unsigned short f2bf(float f) {
  unsigned int u = __float_as_uint(f);
  unsigned int r = u + 0x7FFFu + ((u >> 16) & 1u);
  return (unsigned short)(r >> 16);
}

// ---------------------------------------------------------------------------
// K1: conf scores in FP64 (discrete top-k decision must match f64 np ref)
// ---------------------------------------------------------------------------
__global__ __launch_bounds__(256) void k_conf(
    const float* __restrict__ x, const float* __restrict__ ng, const float* __restrict__ nb,
    const float* __restrict__ cw, const float* __restrict__ cb,
    const float* __restrict__ nu, double* __restrict__ scores) {
  int t = blockIdx.x * 256 + threadIdx.x;
  if (t >= B_ * N_) return;
  int b = t / N_, n = t - b * N_;
  if (n < NG) return;
  const float4* row = (const float4*)(x + (size_t)t * C_);
  float v[C_];
#pragma unroll
  for (int i = 0; i < 16; ++i) {
    float4 r = row[i];
    v[4*i] = r.x; v[4*i+1] = r.y; v[4*i+2] = r.z; v[4*i+3] = r.w;
  }
  double sd = 0.0;
#pragma unroll
  for (int i = 0; i < C_; ++i) sd += (double)v[i];
  double md = sd * (1.0/64.0);
  double vd = 0.0;
#pragma unroll
  for (int i = 0; i < C_; ++i) { double d = (double)v[i] - md; vd += d * d; }
  vd *= (1.0/64.0);
  double rsd = 1.0 / sqrt(vd + 1e-5);
  double conf = (double)cb[0];
#pragma unroll
  for (int i = 0; i < C_; ++i) {
    double xnv = ((double)v[i] - md) * rsd;
    conf += (xnv * (double)ng[i] + (double)nb[i]) * (double)cw[i];
  }
  double u = (double)nu[(size_t)b * NREST + (n - NG)];
  double noise = -log(-log(u + 1e-6) + 1e-6);
  scores[(size_t)b * NREST + (n - NG)] = conf + noise;
}

// ---------------------------------------------------------------------------
// K2: per-batch top-784 of 3087 via bitonic sort of (f64-key, idx) in LDS.
// ---------------------------------------------------------------------------
__global__ __launch_bounds__(256) void k_topk(const double* __restrict__ scores, int* __restrict__ idx) {
  __shared__ unsigned long long ks[4096];
  __shared__ unsigned int is_[4096];
  int b = blockIdx.x;
  int tid = threadIdx.x;
  const double* sc = scores + (size_t)b * NREST;
  for (int i = tid; i < 4096; i += 256) {
    if (i < NREST) {
      long long bits = __double_as_longlong(sc[i]);
      unsigned long long ub = (unsigned long long)bits;
      ub = (bits < 0) ? ~ub : (ub | 0x8000000000000000ULL);  // monotone map
      ks[i] = ~ub;               // ascending key == descending score
      is_[i] = (unsigned int)i;
    } else {
      ks[i] = 0xFFFFFFFFFFFFFFFFULL;
      is_[i] = 0xFFFFFFFFu;
    }
  }
  __syncthreads();
  for (int k = 2; k <= 4096; k <<= 1) {
    for (int j = k >> 1; j > 0; j >>= 1) {
      for (int i = tid; i < 4096; i += 256) {
        int l = i ^ j;
        if (l > i) {
          unsigned long long ka = ks[i], kc = ks[l];
          unsigned int ia = is_[i], ic = is_[l];
          bool agtc = (ka > kc) || (ka == kc && ia > ic);
          bool up = ((i & k) == 0);
          if (up == agtc) { ks[i] = kc; ks[l] = ka; is_[i] = ic; is_[l] = ia; }
        }
      }
      __syncthreads();
    }
  }
  for (int r = tid; r < NSAMP; r += 256)
    idx[(size_t)b * NSAMP + r] = (int)is_[r];
}

// ---------------------------------------------------------------------------
// K3: gather x_down/pos_down rows; LayerNorm(x_down, norm1) -> xn
// ---------------------------------------------------------------------------
__global__ __launch_bounds__(256) void k_gather_ln(
    const float* __restrict__ x, const float* __restrict__ pos, const int* __restrict__ idx,
    const float* __restrict__ n1g, const float* __restrict__ n1b,
    float* __restrict__ xd, float* __restrict__ xn, float* __restrict__ pd) {
  int t = blockIdx.x * 256 + threadIdx.x;
  if (t >= B_ * ND) return;
  int b = t / ND, r = t - b * ND;
  int srcn = (r < NG) ? r : (NG + idx[(size_t)b * NSAMP + (r - NG)]);
  const float4* row = (const float4*)(x + ((size_t)b * N_ + srcn) * C_);
  float4* xdr = (float4*)(xd + (size_t)t * C_);
  float v[C_];
  float s = 0.f, ss = 0.f;
#pragma unroll
  for (int i = 0; i < 16; ++i) {
    float4 rr = row[i];
    xdr[i] = rr;
    v[4*i] = rr.x; v[4*i+1] = rr.y; v[4*i+2] = rr.z; v[4*i+3] = rr.w;
    s += rr.x + rr.y + rr.z + rr.w;
    ss += rr.x*rr.x + rr.y*rr.y + rr.z*rr.z + rr.w*rr.w;
  }
  float m = s * (1.f/64.f);
  float var = ss * (1.f/64.f) - m*m;
  float rs = rsqrtf(var + LN_EPS);
#pragma unroll
  for (int i = 0; i < C_; ++i)
    xn[(size_t)t * C_ + i] = (v[i] - m) * rs * n1g[i] + n1b[i];
  pd[(size_t)2*t]   = pos[((size_t)b * N_ + srcn) * 2];
  pd[(size_t)2*t+1] = pos[((size_t)b * N_ + srcn) * 2 + 1];
}

// ---------------------------------------------------------------------------
// K4: scatter: one WAVE per token, lane = channel; coalesced atomics.
// ---------------------------------------------------------------------------
__global__ __launch_bounds__(256) void k_scatter(
    const float* __restrict__ x, const float* __restrict__ n1g, const float* __restrict__ n1b,
    const float* __restrict__ pos, float* __restrict__ S) {
  int gt = blockIdx.x * 256 + threadIdx.x;
  int tok = gt >> 6, lane = gt & 63;
  if (tok >= B_ * N_) return;
  int b = tok / N_;
  float v = x[(size_t)tok * C_ + lane];
  float s = v, ss = v * v;
#pragma unroll
  for (int m = 32; m > 0; m >>= 1) {
    s += __shfl_xor(s, m);
    ss += __shfl_xor(ss, m);
  }
  float mean = s * (1.f/64.f);
  float var = ss * (1.f/64.f) - mean * mean;
  float rs = rsqrtf(var + LN_EPS);
  double px = fmin(fmax((double)pos[(size_t)2*tok],   0.0), 1.0) * (double)(W_ - 1);
  double py = fmin(fmax((double)pos[(size_t)2*tok+1], 0.0), 1.0) * (double)(H_ - 1);
  int xi = (int)rint(px), yi = (int)rint(py);
  float* base = S + ((size_t)b * HW + yi * W_ + xi) * 65;
  atomicAdd(base + lane, (v - mean) * rs * n1g[lane] + n1b[lane]);
  if (lane == 0) atomicAdd(base + 64, 1.f);
}

// ---------------------------------------------------------------------------
// K5: normalize + masked 3x3 gaussian reconstruct -> conv-patch layout (f32)
// ---------------------------------------------------------------------------
__global__ __launch_bounds__(256) void k_filter(const float* __restrict__ S, float* __restrict__ P) {
  int t = blockIdx.x * 256 + threadIdx.x;
  if (t >= B_ * HW) return;
  int b = t / HW, p = t - b * HW;
  int y = p / W_, x = p - y * W_;
  const float* Sb = S + (size_t)b * HW * 65;
  const float e1 = 0.882496902584595f;   // exp(-1/8)
  const float e2 = 0.778800783071405f;   // exp(-1/4)
  const float Z = 1.f + 4.f * (e1 + e2);
  float m0 = Sb[(size_t)p * 65 + 64];
  float mb0 = m0 > 0.f ? 1.f : 0.f;
  float cfac = mb0 / (m0 + EPS6);
  float scale[9];
  int off[9];
  float mi = 0.f;
  int kk = 0;
#pragma unroll
  for (int dy = -1; dy <= 1; ++dy) {
#pragma unroll
    for (int dx = -1; dx <= 1; ++dx) {
      int ny = y + dy, nx = x + dx;
      float w = ((dx == 0 && dy == 0) ? 1.f : ((dx*dx + dy*dy) == 1 ? e1 : e2)) / Z;
      bool in = (ny >= 0 && ny < H_ && nx >= 0 && nx < W_);
      int np = in ? (ny * W_ + nx) : p;
      float mm = in ? Sb[(size_t)np * 65 + 64] : 0.f;
      float mb = mm > 0.f ? 1.f : 0.f;
      mi += w * mb;
      scale[kk] = in ? (w * mb / (mm + EPS6)) : 0.f;
      off[kk] = np * 65;
      ++kk;
    }
  }
  float inv_mi = (mi > 0.f ? 1.f : 0.f) / (mi + EPS6);
  float outer = (1.f - mb0) * inv_mi;
  int j = (y >> 2) * 14 + (x >> 2);
  int colb = (y & 3) * 4 + (x & 3);
  float* Pr = P + ((size_t)b * NS + j) * 1024 + colb;
  size_t pc = (size_t)p * 65;
  for (int c = 0; c < C_; ++c) {
    float fs = 0.f;
#pragma unroll
    for (int q = 0; q < 9; ++q) fs += scale[q] * Sb[(size_t)off[q] + c];
    Pr[c * 16] = Sb[pc + c] * cfac + outer * fs;
  }
}

// ---------------------------------------------------------------------------
// K6: transpose sr_w (co,ci,ky,kx) -> w_t[kk=ci*16+ky*4+kx][co]
// ---------------------------------------------------------------------------
__global__ __launch_bounds__(256) void k_wt(const float* __restrict__ srw, float* __restrict__ wt) {
  int t = blockIdx.x * 256 + threadIdx.x;
  if (t >= 1024 * 64) return;
  int kk = t >> 6, co = t & 63;
  int ci = kk >> 4, r = kk & 15;
  wt[t] = srw[(((size_t)co * 64 + ci) << 4) + r];
}

// ---------------------------------------------------------------------------
// K6b (ROUND-6): pack fc1/fc2 weights into B-frag-contiguous bf16 layout:
// Wp[kc][quad][n][j] = W[kc*32+quad*8+j][n]  (one 16B chunk per (kc,quad,n))
// ---------------------------------------------------------------------------
__global__ __launch_bounds__(256) void k_wpack(const float* __restrict__ W1, const float* __restrict__ W2,
    unsigned short* __restrict__ W1p, unsigned short* __restrict__ W2p) {
  int t = blockIdx.x * 256 + threadIdx.x;
  if (t >= 65536) return;
  {
    // W1: [128][512] ; kc 0..3, quad 0..3, n 0..511, j 0..7
    int j = t & 7;
    int n = (t >> 3) & 511;
    int qk = t >> 12;            // 0..15
    int quad = qk & 3, kc = qk >> 2;
    int k = kc * 32 + quad * 8 + j;
    W1p[t] = f2bf(W1[(size_t)k * 512 + n]);
  }
  {
    // W2: [512][128] ; kg 0..15, quad 0..3, n 0..127, j 0..7
    int j = t & 7;
    int n = (t >> 3) & 127;
    int qk = t >> 10;            // 0..63
    int quad = qk & 3, kg = qk >> 2;
    int k = kg * 32 + quad * 8 + j;
    W2p[t] = f2bf(W2[(size_t)k * 128 + n]);
  }
}

// ---------------------------------------------------------------------------
// Tiled fp32 GEMM: C[M,N] = A[M,K] @ B[K,N] (+bias)(+add)
// ---------------------------------------------------------------------------
__global__ __launch_bounds__(256) void k_gemm(
    const float* __restrict__ A, const float* __restrict__ Bw,
    const float* __restrict__ bias, const float* __restrict__ add,
    float* __restrict__ Cout, int M, int N, int K) {
  __shared__ float sA[16][68];
  __shared__ float sB[16][64];
  int bm = blockIdx.x * 64, bn = blockIdx.y * 64;
  int tid = threadIdx.x;
  int tx = tid & 15, ty = tid >> 4;
  float acc[4][4] = {{0.f}};
  for (int k0 = 0; k0 < K; k0 += 16) {
    int e = tid << 2;
    int am = e >> 4, ak = e & 15;
    float4 a4 = *(const float4*)(A + (size_t)(bm + am) * K + k0 + ak);
    sA[ak + 0][am] = a4.x; sA[ak + 1][am] = a4.y; sA[ak + 2][am] = a4.z; sA[ak + 3][am] = a4.w;
    int bk = e >> 6, nn = e & 63;
    float4 b4 = *(const float4*)(Bw + (size_t)(k0 + bk) * N + bn + nn);
    *(float4*)&sB[bk][nn] = b4;
    __syncthreads();
#pragma unroll
    for (int kk = 0; kk < 16; ++kk) {
      float a[4], bb[4];
#pragma unroll
      for (int i = 0; i < 4; ++i) a[i] = sA[kk][ty * 4 + i];
#pragma unroll
      for (int i = 0; i < 4; ++i) bb[i] = sB[kk][tx * 4 + i];
#pragma unroll
      for (int i = 0; i < 4; ++i)
#pragma unroll
        for (int jj = 0; jj < 4; ++jj) acc[i][jj] += a[i] * bb[jj];
    }
    __syncthreads();
  }
#pragma unroll
  for (int i = 0; i < 4; ++i) {
    int row = bm + ty * 4 + i;
#pragma unroll
    for (int jj = 0; jj < 4; ++jj) {
      int col = bn + tx * 4 + jj;
      float v = acc[i][jj];
      if (bias) v += bias[col];
      if (add) v += add[(size_t)row * N + col];
      Cout[(size_t)row * N + col] = v;
    }
  }
}

// ---------------------------------------------------------------------------
// K-MLP (ROUND-6 REWRITE): MFMA bf16. out += gelu(A@W1+b1)@W2+b2.
// Block = 64 rows, 4 waves; wave = 16-row strip, all 128 hidden cols/chunk.
// A staged bf16 XOR-swizzled in LDS; H per-wave bf16 tile (C->A transpose);
// W1p/W2p B-frags loaded straight from global (L2-resident, coalesced 16B).
// LDS = 16KB (A) + 16KB (H) = 32KB -> 4 blocks/CU.
// ---------------------------------------------------------------------------
__global__ __launch_bounds__(256) void k_mlp(
    const float* __restrict__ A, const unsigned short* __restrict__ W1p, const float* __restrict__ b1,
    const unsigned short* __restrict__ W2p, const float* __restrict__ b2, float* __restrict__ out) {
  __shared__ __align__(16) unsigned short sA[64 * 128];
  __shared__ __align__(16) unsigned short sH[4][16 * 128];
  int bm = blockIdx.x * 64;
  int tid = threadIdx.x;
  int wv = tid >> 6, lane = tid & 63, quad = lane >> 4, l16 = lane & 15;

  // ---- stage A: 64x128 fp32 -> bf16, 16B chunks swizzled by (ck ^ row) ----
  for (int t = tid; t < 64 * 16; t += 256) {
    int row = t >> 4, ck = t & 15;
    const float* src = A + (size_t)(bm + row) * 128 + ck * 8;
    float4 a = *(const float4*)src;
    float4 c = *(const float4*)(src + 4);
    short8 p;
    p[0]=(short)f2bf(a.x); p[1]=(short)f2bf(a.y); p[2]=(short)f2bf(a.z); p[3]=(short)f2bf(a.w);
    p[4]=(short)f2bf(c.x); p[5]=(short)f2bf(c.y); p[6]=(short)f2bf(c.z); p[7]=(short)f2bf(c.w);
    *(short8*)&sA[row * 128 + (((ck ^ row) & 15) << 3)] = p;
  }
  __syncthreads();

  f32x4 oacc[8];
#pragma unroll
  for (int ct = 0; ct < 8; ++ct) oacc[ct] = (f32x4){0.f, 0.f, 0.f, 0.f};

  for (int hc = 0; hc < 4; ++hc) {
    // ---- GEMM1: H[16x128] = A-strip @ W1[:, hc*128..+128) ----
    f32x4 acc1[8];
#pragma unroll
    for (int ct = 0; ct < 8; ++ct) acc1[ct] = (f32x4){0.f, 0.f, 0.f, 0.f};
#pragma unroll
    for (int kc = 0; kc < 4; ++kc) {
      int row = wv * 16 + l16;
      int ck = kc * 4 + quad;
      short8 af = *(const short8*)&sA[row * 128 + (((ck ^ row) & 15) << 3)];
#pragma unroll
      for (int ct = 0; ct < 8; ++ct) {
        int n = hc * 128 + ct * 16 + l16;
        short8 bf = *(const short8*)&W1p[(((size_t)kc * 4 + quad) * 512 + n) << 3];
        acc1[ct] = __builtin_amdgcn_mfma_f32_16x16x32_bf16(af, bf, acc1[ct], 0, 0, 0);
      }
    }
    // ---- bias + exact GELU -> per-wave H tile (bf16, swizzled) ----
    __syncthreads();   // prior GEMM2 reads of sH done (all waves)
#pragma unroll
    for (int ct = 0; ct < 8; ++ct)
#pragma unroll
      for (int r = 0; r < 4; ++r) {
        float v = acc1[ct][r] + b1[hc * 128 + ct * 16 + l16];
        v = 0.5f * v * (1.f + erff(v * 0.70710678118654752f));
        int rit = quad * 4 + r;
        int col = ct * 16 + l16;
        int ck = col >> 3;
        sH[wv][rit * 128 + (((ck ^ rit) & 15) << 3) + (col & 7)] = f2bf(v);
      }
    __syncthreads();   // H visible
    // ---- GEMM2: O += H @ W2[hc*128..+128, :] ----
#pragma unroll
    for (int kc = 0; kc < 4; ++kc) {
      int ck = kc * 4 + quad;
      short8 hf = *(const short8*)&sH[wv][l16 * 128 + (((ck ^ l16) & 15) << 3)];
      int kg = hc * 4 + kc;
#pragma unroll
      for (int ct = 0; ct < 8; ++ct) {
        int n = ct * 16 + l16;
        short8 bf = *(const short8*)&W2p[(((size_t)kg * 4 + quad) * 128 + n) << 3];
        oacc[ct] = __builtin_amdgcn_mfma_f32_16x16x32_bf16(hf, bf, oacc[ct], 0, 0, 0);
      }
    }
  }
  // ---- out += O + b2 (C-layout: col=l16, row=quad*4+r) ----
#pragma unroll
  for (int ct = 0; ct < 8; ++ct)
#pragma unroll
    for (int r = 0; r < 4; ++r) {
      int row = bm + wv * 16 + quad * 4 + r;
      int col = ct * 16 + l16;
      out[(size_t)row * 128 + col] += oacc[ct][r] + b2[col];
    }
}

// ---------------------------------------------------------------------------
// LayerNorm kernels (dim 128 / dim 64), one thread per row
// ---------------------------------------------------------------------------
__global__ __launch_bounds__(256) void k_ln128(const float* __restrict__ in, const float* __restrict__ g,
    const float* __restrict__ bb, float* __restrict__ out, int rows) {
  int t = blockIdx.x * 256 + threadIdx.x;
  if (t >= rows) return;
  const float4* row = (const float4*)(in + (size_t)t * 128);
  float4 v[32];
  float s = 0.f, ss = 0.f;
#pragma unroll
  for (int i = 0; i < 32; ++i) {
    float4 r = row[i]; v[i] = r;
    s += r.x + r.y + r.z + r.w;
    ss += r.x*r.x + r.y*r.y + r.z*r.z + r.w*r.w;
  }
  float m = s * (1.f/128.f);
  float var = ss * (1.f/128.f) - m*m;
  float rs = rsqrtf(var + LN_EPS);
  float4* orow = (float4*)(out + (size_t)t * 128);
#pragma unroll
  for (int i = 0; i < 32; ++i) {
    float4 r = v[i];
    float4 o;
    o.x = (r.x - m) * rs * g[4*i+0] + bb[4*i+0];
    o.y = (r.y - m) * rs * g[4*i+1] + bb[4*i+1];
    o.z = (r.z - m) * rs * g[4*i+2] + bb[4*i+2];
    o.w = (r.w - m) * rs * g[4*i+3] + bb[4*i+3];
    orow[i] = o;
  }
}

__global__ __launch_bounds__(256) void k_ln64(const float* __restrict__ in, const float* __restrict__ g,
    const float* __restrict__ bb, float* __restrict__ out, int rows) {
  int t = blockIdx.x * 256 + threadIdx.x;
  if (t >= rows) return;
  const float4* row = (const float4*)(in + (size_t)t * 64);
  float v[64];
  float s = 0.f, ss = 0.f;
#pragma unroll
  for (int i = 0; i < 16; ++i) {
    float4 r = row[i];
    v[4*i] = r.x; v[4*i+1] = r.y; v[4*i+2] = r.z; v[4*i+3] = r.w;
    s += r.x + r.y + r.z + r.w;
    ss += r.x*r.x + r.y*r.y + r.z*r.z + r.w*r.w;
  }
  float m = s * (1.f/64.f);
  float var = ss * (1.f/64.f) - m*m;
  float rs = rsqrtf(var + LN_EPS);
#pragma unroll
  for (int i = 0; i < 64; ++i)
    out[(size_t)t * 64 + i] = (v[i] - m) * rs * g[i] + bb[i];
}

// ---------------------------------------------------------------------------
// K7: MFMA attention (round-5), unchanged.
// ---------------------------------------------------------------------------
__global__ __launch_bounds__(256) void k_attn(const float* __restrict__ q,
    const float* __restrict__ kg, const float* __restrict__ vg, float* __restrict__ o) {
  __shared__ __align__(16) unsigned short ldsKP[14848];
  __shared__ __align__(16) unsigned short ldsV[16128];
  int blk = blockIdx.x;
  int chunk = blk % 14;
  int bh = blk / 14;
  int h = bh & 1, b = bh >> 1;
  int tid = threadIdx.x;
  int wv = tid >> 6, lane = tid & 63;
  int quad = lane >> 4, l16 = lane & 15;

  const float* kb = kg + (size_t)b * NS * 128 + h * 64;
  const float* vb = vg + (size_t)b * NS * 128 + h * 64;

  for (int t = tid; t < KPAD * 8; t += 256) {
    int key = t >> 3, ck = t & 7;
    short8 pk, pv;
    if (key < NS) {
      const float* ksrc = kb + (size_t)key * 128 + ck * 8;
      const float* vsrc = vb + (size_t)key * 128 + ck * 8;
      float4 a = *(const float4*)ksrc;
      float4 c = *(const float4*)(ksrc + 4);
      pk[0]=(short)f2bf(a.x); pk[1]=(short)f2bf(a.y); pk[2]=(short)f2bf(a.z); pk[3]=(short)f2bf(a.w);
      pk[4]=(short)f2bf(c.x); pk[5]=(short)f2bf(c.y); pk[6]=(short)f2bf(c.z); pk[7]=(short)f2bf(c.w);
      float4 e = *(const float4*)vsrc;
      float4 g = *(const float4*)(vsrc + 4);
      pv[0]=(short)f2bf(e.x); pv[1]=(short)f2bf(e.y); pv[2]=(short)f2bf(e.z); pv[3]=(short)f2bf(e.w);
      pv[4]=(short)f2bf(g.x); pv[5]=(short)f2bf(g.y); pv[6]=(short)f2bf(g.z); pv[7]=(short)f2bf(g.w);
    } else {
      pk = (short8)0; pv = (short8)0;
    }
    *(short8*)&ldsKP[key * 64 + ((ck ^ (key & 7)) << 3)] = pk;
    *(short8*)&ldsV[key * 72 + ck * 8] = pv;
  }

  int qrow = chunk * 64 + wv * 16 + l16;
  int qrowc = qrow < ND ? qrow : ND - 1;
  const float* qsrc = q + ((size_t)b * ND + qrowc) * 128 + h * 64 + quad * 8;
  short8 aq0, aq1;
  {
    float4 a = *(const float4*)qsrc;
    float4 c = *(const float4*)(qsrc + 4);
    aq0[0]=(short)f2bf(a.x); aq0[1]=(short)f2bf(a.y); aq0[2]=(short)f2bf(a.z); aq0[3]=(short)f2bf(a.w);
    aq0[4]=(short)f2bf(c.x); aq0[5]=(short)f2bf(c.y); aq0[6]=(short)f2bf(c.z); aq0[7]=(short)f2bf(c.w);
    float4 e = *(const float4*)(qsrc + 32);
    float4 g = *(const float4*)(qsrc + 36);
    aq1[0]=(short)f2bf(e.x); aq1[1]=(short)f2bf(e.y); aq1[2]=(short)f2bf(e.z); aq1[3]=(short)f2bf(e.w);
    aq1[4]=(short)f2bf(g.x); aq1[5]=(short)f2bf(g.y); aq1[6]=(short)f2bf(g.z); aq1[7]=(short)f2bf(g.w);
  }
  __syncthreads();

  f32x4 acc[14];
#pragma unroll
  for (int ct = 0; ct < 14; ++ct) {
    int key = ct * 16 + l16;
    short8 bk0 = *(const short8*)&ldsKP[key * 64 + ((quad ^ (key & 7)) << 3)];
    short8 bk1 = *(const short8*)&ldsKP[key * 64 + (((4 + quad) ^ (key & 7)) << 3)];
    f32x4 z = {0.f, 0.f, 0.f, 0.f};
    z = __builtin_amdgcn_mfma_f32_16x16x32_bf16(aq0, bk0, z, 0, 0, 0);
    z = __builtin_amdgcn_mfma_f32_16x16x32_bf16(aq1, bk1, z, 0, 0, 0);
    acc[ct] = z;
  }

  const float scale = 0.17677669529663687f;  // 32^-0.5
  float rmax[4] = {-1e30f, -1e30f, -1e30f, -1e30f};
#pragma unroll
  for (int ct = 0; ct < 14; ++ct) {
    bool msk = (ct * 16 + l16) >= NS;
#pragma unroll
    for (int r = 0; r < 4; ++r) {
      float sv = msk ? -1e30f : acc[ct][r] * scale;
      acc[ct][r] = sv;
      rmax[r] = fmaxf(rmax[r], sv);
    }
  }
#pragma unroll
  for (int m = 1; m < 16; m <<= 1)
#pragma unroll
    for (int r = 0; r < 4; ++r) rmax[r] = fmaxf(rmax[r], __shfl_xor(rmax[r], m));
  float rsum[4] = {0.f, 0.f, 0.f, 0.f};
#pragma unroll
  for (int ct = 0; ct < 14; ++ct)
#pragma unroll
    for (int r = 0; r < 4; ++r) {
      float e = __expf(acc[ct][r] - rmax[r]);
      acc[ct][r] = e;
      rsum[r] += e;
    }
#pragma unroll
  for (int m = 1; m < 16; m <<= 1)
#pragma unroll
    for (int r = 0; r < 4; ++r) rsum[r] += __shfl_xor(rsum[r], m);
  float rinv[4];
#pragma unroll
  for (int r = 0; r < 4; ++r) rinv[r] = 1.f / rsum[r];

  __syncthreads();

#pragma unroll
  for (int ct = 0; ct < 14; ++ct)
#pragma unroll
    for (int r = 0; r < 4; ++r) {
      int prow = wv * 16 + quad * 4 + r;
      ldsKP[prow * 232 + ct * 16 + l16] = f2bf(acc[ct][r] * rinv[r]);
    }
  __syncthreads();

  f32x4 oacc[4];
#pragma unroll
  for (int ot = 0; ot < 4; ++ot) oacc[ot] = (f32x4){0.f, 0.f, 0.f, 0.f};
#pragma unroll
  for (int kc = 0; kc < 7; ++kc) {
    short8 ap = *(const short8*)&ldsKP[(wv * 16 + l16) * 232 + kc * 32 + quad * 8];
    int keybase = kc * 32 + quad * 8;
#pragma unroll
    for (int ot = 0; ot < 4; ++ot) {
      int dcol = ot * 16 + l16;
      short8 bv;
#pragma unroll
      for (int j = 0; j < 8; ++j) bv[j] = (short)ldsV[(keybase + j) * 72 + dcol];
      oacc[ot] = __builtin_amdgcn_mfma_f32_16x16x32_bf16(ap, bv, oacc[ot], 0, 0, 0);
    }
  }

#pragma unroll
  for (int ot = 0; ot < 4; ++ot)
#pragma unroll
    for (int r = 0; r < 4; ++r) {
      int rowg = chunk * 64 + wv * 16 + quad * 4 + r;
      if (rowg < ND)
        o[((size_t)b * ND + rowg) * 128 + h * 64 + ot * 16 + l16] = oacc[ot][r];
    }
}

// ---------------------------------------------------------------------------
// K8: bilinear grid-sample of pos_embed at pos_down, accumulate into out
// ---------------------------------------------------------------------------
__global__ __launch_bounds__(256) void k_posfeat(const float* __restrict__ pd,
    const float* __restrict__ pe, float* __restrict__ out) {
  int t = blockIdx.x * 256 + threadIdx.x;
  int row = t >> 5, lane = t & 31;
  if (row >= B_ * ND) return;
  float gx = pd[(size_t)2*row] * 2.f - 1.f;
  float gy = pd[(size_t)2*row+1] * 2.f - 1.f;
  float ix = ((gx + 1.f) * 56.f - 1.f) * 0.5f;
  float iy = ((gy + 1.f) * 56.f - 1.f) * 0.5f;
  float x0 = floorf(ix), y0 = floorf(iy);
  float wx1 = ix - x0, wy1 = iy - y0;
  float wx0 = 1.f - wx1, wy0 = 1.f - wy1;
  float4 acc = make_float4(0.f, 0.f, 0.f, 0.f);
#pragma unroll
  for (int cy = 0; cy < 2; ++cy) {
#pragma unroll
    for (int cx = 0; cx < 2; ++cx) {
      float xc = x0 + (float)cx, yc = y0 + (float)cy;
      float wgt = (cx ? wx1 : wx0) * (cy ? wy1 : wy0);
      bool valid = (xc >= 0.f) && (xc < 56.f) && (yc >= 0.f) && (yc < 56.f);
      if (valid) {
        int lin = (int)yc * 56 + (int)xc;
        float4 pv = ((const float4*)(pe + (size_t)lin * 128))[lane];
        acc.x += wgt * pv.x; acc.y += wgt * pv.y;
        acc.z += wgt * pv.z; acc.w += wgt * pv.w;
      }
    }
  }
  float4* op = (float4*)(out + (size_t)row * 128) + lane;
  float4 cur = *op;
  cur.x += acc.x; cur.y += acc.y; cur.z += acc.z; cur.w += acc.w;
  *op = cur;
}

// ---------------------------------------------------------------------------
// launcher
// ---------------------------------------------------------------------------
extern "C" void kernel_launch(void* const* d_in, const int* in_sizes, int n_in,
                              void* d_out, int out_size, void* d_ws, size_t ws_size,
                              hipStream_t stream) {
  const float* x      = (const float*)d_in[0];
  const float* pos    = (const float*)d_in[1];
  const float* pe     = (const float*)d_in[2];
  const float* nu     = (const float*)d_in[3];
  const float* norm_g = (const float*)d_in[4];
  const float* norm_b = (const float*)d_in[5];
  const float* conf_w = (const float*)d_in[6];
  const float* conf_b = (const float*)d_in[7];
  const float* n1g    = (const float*)d_in[8];
  const float* n1b    = (const float*)d_in[9];
  const float* q_w    = (const float*)d_in[10];
  const float* k_w    = (const float*)d_in[11];
  const float* v_w    = (const float*)d_in[12];
  const float* proj_w = (const float*)d_in[13];
  const float* proj_b = (const float*)d_in[14];
  const float* sr_w   = (const float*)d_in[15];
  const float* sr_b   = (const float*)d_in[16];
  const float* srn_g  = (const float*)d_in[17];
  const float* srn_b  = (const float*)d_in[18];
  const float* fc_w   = (const float*)d_in[19];
  const float* fc_b   = (const float*)d_in[20];
  const float* n2g    = (const float*)d_in[21];
  const float* n2b    = (const float*)d_in[22];
  const float* fc1_w  = (const float*)d_in[23];
  const float* fc1_b  = (const float*)d_in[24];
  const float* fc2_w  = (const float*)d_in[25];
  const float* fc2_b  = (const float*)d_in[26];

  char* ws = (char*)d_ws;
  // workspace layout (bytes); total 190,578,688
  double*         scores = (double*)(ws + 0);                //  1,580,544
  int*            idx    = (int*)(ws + 1605632);             //    200,704
  float*          xd     = (float*)(ws + 1835008);           // 13,647,872
  float*          xn     = (float*)(ws + 15728640);          // 13,647,872
  float*          pd     = (float*)(ws + 29491200);          //    426,496
  float*          qb     = (float*)(ws + 30408704);          // 27,295,744; P alias; later O2
  float*          ob     = (float*)(ws + 58720256);          // 27,295,744; P tail alias; later xn2
  float*          wt     = (float*)(ws + 86507520);          //    262,144 (ends 86,769,664)
  unsigned short* W1p    = (unsigned short*)(ws + 86769664); //    131,072
  unsigned short* W2p    = (unsigned short*)(ws + 86900736); //    131,072 (ends 87,031,808)
  char*           big    = ws + 87031808;                    // 103,546,880 region
  float*          S      = (float*)big;                      // 52,183,040 (exclusive; dead after filter)
  float*          P      = (float*)(ws + 30408704);          // 51,380,224 (alias qb..ob; dead after conv)
  float*          xs_c   = (float*)big;                      //  3,211,264 (reuses S after filter)
  float*          xs_n   = (float*)(big + 3211264);          //  3,211,264
  float*          kbuf   = (float*)(big + 6422528);          //  6,422,528
  float*          vbuf   = (float*)(big + 12845056);         //  6,422,528
  float*          O2     = qb;
  float*          xn2    = ob;
  float*          out    = (float*)d_out;

  // 1) f64 conf+gumbel scores
  k_conf<<<(B_ * N_) / 256, 256, 0, stream>>>(x, norm_g, norm_b, conf_w, conf_b, nu, scores);
  // 2) top-784 per batch (f64 keys)
  k_topk<<<B_, 256, 0, stream>>>(scores, idx);
  // 3) gather + LN(norm1)
  k_gather_ln<<<(B_ * ND + 255) / 256, 256, 0, stream>>>(x, pos, idx, n1g, n1b, xd, xn, pd);
  // 4) token2map scatter (wave-per-token, coalesced atomics, f64 binning)
  hipMemsetAsync(S, 0, (size_t)B_ * HW * 65 * sizeof(float), stream);
  k_scatter<<<(B_ * N_ * 64) / 256, 256, 0, stream>>>(x, n1g, n1b, pos, S);
  // 5) normalize + gaussian reconstruct -> patch layout (f32)
  k_filter<<<(B_ * HW) / 256, 256, 0, stream>>>(S, P);
  // 6) conv weights transpose + MLP weight pack; conv-as-GEMM; srnorm
  k_wt<<<(1024 * 64) / 256, 256, 0, stream>>>(sr_w, wt);
  k_wpack<<<65536 / 256, 256, 0, stream>>>(fc1_w, fc2_w, W1p, W2p);
  dim3 g_conv(NS * B_ / 64, 1);
  k_gemm<<<g_conv, 256, 0, stream>>>(P, wt, sr_b, nullptr, xs_c, B_ * NS, 64, 1024);
  k_ln64<<<(B_ * NS + 255) / 256, 256, 0, stream>>>(xs_c, srn_g, srn_b, xs_n, B_ * NS);
  // 7) k, v, q projections (q GEMM overwrites P region -- P is dead by now)
  dim3 g_kv(B_ * NS / 64, 2);
  k_gemm<<<g_kv, 256, 0, stream>>>(xs_n, k_w, nullptr, nullptr, kbuf, B_ * NS, 128, 64);
  k_gemm<<<g_kv, 256, 0, stream>>>(xs_n, v_w, nullptr, nullptr, vbuf, B_ * NS, 128, 64);
  dim3 g_row(B_ * ND / 64, 2);
  k_gemm<<<g_row, 256, 0, stream>>>(xn, q_w, nullptr, nullptr, qb, B_ * ND, 128, 64);
  // 8) attention (MFMA bf16)
  k_attn<<<B_ * 2 * 14, 256, 0, stream>>>(qb, kbuf, vbuf, ob);
  // 9) x2 = x_down@fc_w + fc_b + (o@proj_w + proj_b)  -> d_out
  k_gemm<<<g_row, 256, 0, stream>>>(ob, proj_w, proj_b, nullptr, O2, B_ * ND, 128, 128);
  k_gemm<<<g_row, 256, 0, stream>>>(xd, fc_w, fc_b, O2, out, B_ * ND, 128, 64);
  // 10) MLP: LN128 then MFMA fused fc1+gelu+fc2 (accumulates into out)
  k_ln128<<<(B_ * ND + 255) / 256, 256, 0, stream>>>(out, n2g, n2b, xn2, B_ * ND);
  k_mlp<<<B_ * ND / 64, 256, 0, stream>>>(xn2, W1p, fc1_b, W2p, fc2_b, out);
  // 11) + pos_feat (bilinear grid sample)
  k_posfeat<<<(B_ * ND * 32) / 256, 256, 0, stream>>>(pd, pe, out);
}